// Round 1
// baseline (813.752 us; speedup 1.0000x reference)
//
#include <hip/hip_runtime.h>
#include <math.h>

// Problem constants
#define BB   16      // batch
#define IC   8       // in capsules
#define BI   128     // BB*IC
#define CIN  16      // conv in channels
#define WH   128     // input spatial
#define OWH  65      // output spatial (stride 2, pad 2, k 4)
#define NPIX (OWH*OWH)   // 4225
#define OC   8       // out capsules
#define COUT 16      // out channel per capsule
#define NOC  128     // OC*Cout
#define KTOT 256     // CIN*4*4
#define KC   64      // (fp32 fallback chunk)
#define NCHUNK 4

// MFMA kernel: K chunked by 32 (one mfma-K per chunk), 8 chunks
#define NCHM 8

typedef unsigned short ushortT;
typedef __bf16 bf16x8 __attribute__((ext_vector_type(8)));
typedef float  f32x4  __attribute__((ext_vector_type(4)));

union PackB { ushort4 h[2]; bf16x8 v; };

__device__ __forceinline__ ushortT f2bf(float f) {
    unsigned u = __float_as_uint(f);
    unsigned r = (u + 0x7fffu + ((u >> 16) & 1u)) >> 16;
    return (ushortT)r;
}

// ---------------------------------------------------------------------------
// Pre-pass 1: x fp32 -> bf16 (same layout)
// ---------------------------------------------------------------------------
__global__ void cvt_x_kernel(const float4* __restrict__ x,
                             ushort4* __restrict__ xbf, int n4)
{
    int stride = gridDim.x * blockDim.x;
    for (int i = blockIdx.x * blockDim.x + threadIdx.x; i < n4; i += stride) {
        float4 v = x[i];
        ushort4 o;
        o.x = f2bf(v.x); o.y = f2bf(v.y); o.z = f2bf(v.z); o.w = f2bf(v.w);
        xbf[i] = o;
    }
}

// ---------------------------------------------------------------------------
// Pre-pass 2: W fp32 [oc][k] -> bf16 prepacked fragment image:
//   Wbf[(kpg*128+oc)*8 + j]   (k = kpg*8 + j, kpg = 0..31)
// ---------------------------------------------------------------------------
__global__ void prep_w_kernel(const float* __restrict__ W,
                              ushortT* __restrict__ Wbf)
{
    int idx = blockIdx.x * 256 + threadIdx.x;   // 32768 total
    int oc = idx >> 8, k = idx & 255;
    int kpg = k >> 3, j = k & 7;
    Wbf[((size_t)kpg * 128 + oc) * 8 + j] = f2bf(W[idx]);
}

// ---------------------------------------------------------------------------
// Fused MFMA kernel, 512 threads (8 waves). Wave w owns a 64x32 C quadrant:
// rows [64*(w>>2), +64) x cols [32*(w&3), +32) as 4x2 tiles of 16x16.
//
// v2: NO LDS staging, NO K-loop barriers. Each lane loads its MFMA fragments
// directly from global:
//   A-frag (lane q,cL; tile mt): rows ra=row0+(q&1)*2 and ra+1,
//     cols col0..col0+3 of image bi = mrow_base+mt*16+cL, channel ci=2*kc+(q>>1)
//     -> two contiguous 8B pieces of xbf (identical bytes the old staging
//        loader fetched, just consumed in-register).
//   B-frag: 16B contiguous in prepacked Wbf at ((kc*4+q)*128 + col)*8.
// Addresses are induction variables (+2*WH*WH elems / chunk for A, +4096 for B).
// Waves run the whole GEMM independently; only routing synchronizes.
// C/D: col=lane&15 -> oc-col c, row=4*quad+reg -> (b,i).
// ---------------------------------------------------------------------------
__launch_bounds__(512, 4)
__global__ void capsconv_mfma(const ushortT* __restrict__ xbf,
                              const ushortT* __restrict__ Wbf,
                              const float* __restrict__ bias,
                              float* __restrict__ outbuf,
                              const int direct_out)
{
    __shared__ float cijs[64];       // [o][i]
    __shared__ float bijs[64];       // [o][i] (written/read by wave 0 only)
    __shared__ float aTmp[16 * 64];  // [b][o*8+i]

    const int t  = threadIdx.x;      // 0..511
    const int g8 = blockIdx.x;
    int p = (g8 & 7) * 529 + (g8 >> 3);     // XCD-contiguous pixel strips
    if (p >= NPIX) return;

    const int w  = t >> 6;       // wave id 0..7
    const int ln = t & 63;
    const int q  = ln >> 4;      // quad
    const int cL = ln & 15;      // lane col (c within tile)
    const int h  = q & 1;        // i-half
    const int mrow_base = 64 * (w >> 2);   // 0 or 64
    const int ncol_base = 32 * (w & 3);    // 0,32,64,96

    const int px = p / OWH;
    const int py = p % OWH;
    const int row0 = 2 * px - 2;
    const int col0 = 2 * py - 2;
    const bool interior = (px >= 1 && px <= 63 && py >= 1 && py <= 63);

    f32x4 acc[4][2];
#pragma unroll
    for (int mt = 0; mt < 4; ++mt)
#pragma unroll
        for (int nt = 0; nt < 2; ++nt) acc[mt][nt] = (f32x4){0.f, 0.f, 0.f, 0.f};

    const int ci0 = q >> 1;              // channel for chunk 0 (this lane)
    const int ra  = row0 + (q & 1) * 2;  // window row (fixed across chunks)

    // ---------------- GEMM: direct-load K loop, zero barriers ----------------
    if (interior) {
        int aoff[4];
#pragma unroll
        for (int mt = 0; mt < 4; ++mt) {
            const int bi = mrow_base + mt * 16 + cL;
            aoff[mt] = ((bi * CIN + ci0) * WH + ra) * WH + col0;
        }
        int boff = (q * 128 + ncol_base + cL) * 8;   // elems; nt stride = 128

#pragma unroll
        for (int kc = 0; kc < NCHM; ++kc) {
            bf16x8 af[4], bfr[2];
#pragma unroll
            for (int mt = 0; mt < 4; ++mt) {
                PackB pk;
                pk.h[0] = *(const ushort4*)(xbf + aoff[mt]);
                pk.h[1] = *(const ushort4*)(xbf + aoff[mt] + WH);
                af[mt] = pk.v;
                aoff[mt] += 2 * WH * WH;             // ci += 2
            }
#pragma unroll
            for (int nt = 0; nt < 2; ++nt)
                bfr[nt] = *(const bf16x8*)(Wbf + boff + nt * 128);
            boff += 4096;                            // kpg += 4
#pragma unroll
            for (int mt = 0; mt < 4; ++mt)
#pragma unroll
                for (int nt = 0; nt < 2; ++nt)
                    acc[mt][nt] = __builtin_amdgcn_mfma_f32_16x16x32_bf16(
                        af[mt], bfr[nt], acc[mt][nt], 0, 0, 0);
        }
    } else {
        int boff = (q * 128 + ncol_base + cL) * 8;
        for (int kc = 0; kc < NCHM; ++kc) {
            bf16x8 af[4], bfr[2];
            const int ci = 2 * kc + ci0;
#pragma unroll
            for (int mt = 0; mt < 4; ++mt) {
                const int bi = mrow_base + mt * 16 + cL;
                ushort4 v0, v1;
                ushortT* pv0 = (ushortT*)&v0;
                ushortT* pv1 = (ushortT*)&v1;
#pragma unroll
                for (int cc = 0; cc < 4; ++cc) {
                    const int col = col0 + cc;
                    const bool okc = (col >= 0 && col < WH);
                    const int ix0 = ((bi * CIN + ci) * WH + ra) * WH + col;
                    pv0[cc] = (okc && ra >= 0 && ra < WH) ? xbf[ix0] : (ushortT)0;
                    pv1[cc] = (okc && ra + 1 >= 0 && ra + 1 < WH) ? xbf[ix0 + WH] : (ushortT)0;
                }
                PackB pk; pk.h[0] = v0; pk.h[1] = v1;
                af[mt] = pk.v;
            }
#pragma unroll
            for (int nt = 0; nt < 2; ++nt)
                bfr[nt] = *(const bf16x8*)(Wbf + boff + nt * 128);
            boff += 4096;
#pragma unroll
            for (int mt = 0; mt < 4; ++mt)
#pragma unroll
                for (int nt = 0; nt < 2; ++nt)
                    acc[mt][nt] = __builtin_amdgcn_mfma_f32_16x16x32_bf16(
                        af[mt], bfr[nt], acc[mt][nt], 0, 0, 0);
        }
    }

    // bias epilogue
#pragma unroll
    for (int nt = 0; nt < 2; ++nt) {
        const float bv = bias[ncol_base + nt * 16 + cL];
#pragma unroll
        for (int mt = 0; mt < 4; ++mt) acc[mt][nt] += bv;
    }

    // ---------------- dynamic routing (3 iters) ----------------
    // iter 0: b_ij = 0 -> c_ij = 1/8 exactly (no softmax needed).
    for (int it = 0; it < 3; ++it) {
        float4 cf4[2];
        if (it == 0) {
#pragma unroll
            for (int nt = 0; nt < 2; ++nt)
                cf4[nt] = make_float4(0.125f, 0.125f, 0.125f, 0.125f);
        } else {
            // cijs already visible (barrier at end of previous boundary)
#pragma unroll
            for (int nt = 0; nt < 2; ++nt)
                cf4[nt] = *(const float4*)&cijs[(2 * (w & 3) + nt) * 8 + 4 * h];
        }

#pragma unroll
        for (int mt = 0; mt < 4; ++mt) {
            const int b = 8 * (w >> 2) + 2 * mt + (q >> 1);
#pragma unroll
            for (int nt = 0; nt < 2; ++nt) {
                const int o = 2 * (w & 3) + nt;
                const float4 cf = cf4[nt];
                float sp = cf.x * acc[mt][nt][0] + cf.y * acc[mt][nt][1]
                         + cf.z * acc[mt][nt][2] + cf.w * acc[mt][nt][3];
                float s = sp + __shfl_xor(sp, 16);
                float ssq = s * s;
#pragma unroll
                for (int d = 1; d < 16; d <<= 1) ssq += __shfl_xor(ssq, d);
                const float scale = sqrtf(ssq) * __builtin_amdgcn_rcpf(1.f + ssq);
                const float vj = s * scale;

                if (it == 2) {
                    if (q == 0 || q == 2) {
                        if (direct_out)
                            outbuf[(size_t)(b * NOC + o * 16 + cL) * NPIX + p] = vj;
                        else
                            outbuf[(size_t)p * 2048 + b * NOC + o * 16 + cL] = vj;
                    }
                } else {
                    f32x4 ap = acc[mt][nt] * vj;
#pragma unroll
                    for (int d = 1; d < 16; d <<= 1) {
                        ap[0] += __shfl_xor(ap[0], d);
                        ap[1] += __shfl_xor(ap[1], d);
                        ap[2] += __shfl_xor(ap[2], d);
                        ap[3] += __shfl_xor(ap[3], d);
                    }
                    if (cL == 0) {
                        float* dst = &aTmp[b * 64 + o * 8 + 4 * h];
                        dst[0] = ap[0]; dst[1] = ap[1]; dst[2] = ap[2]; dst[3] = ap[3];
                    }
                }
            }
        }
        if (it < 2) {
            __syncthreads();   // aTmp writes visible
            if (t < 64) {
                // fused: bij update + softmax, all in wave 0 (lane = o*8+i)
                float sum = 0.f;
#pragma unroll
                for (int b = 0; b < BB; ++b) sum += aTmp[b * 64 + t];
                float bij = (it == 0 ? 0.f : bijs[t]) + sum * (1.f / 16.f);
                bijs[t] = bij;   // wave-0 local across iterations
                float mx = bij;
                mx = fmaxf(mx, __shfl_xor(mx, 1));
                mx = fmaxf(mx, __shfl_xor(mx, 2));
                mx = fmaxf(mx, __shfl_xor(mx, 4));
                float e = __expf(bij - mx);
                float se = e;
                se += __shfl_xor(se, 1);
                se += __shfl_xor(se, 2);
                se += __shfl_xor(se, 4);
                cijs[t] = e * __builtin_amdgcn_rcpf(se);
            }
            __syncthreads();   // cijs (and aTmp reads) done
        }
    }
}

// ---------------------------------------------------------------------------
// [pixel][boc] -> [boc][pixel] tiled transpose
// ---------------------------------------------------------------------------
__global__ void transpose_kernel(const float* __restrict__ vtmp,
                                 float* __restrict__ out)
{
    __shared__ float tile[32][33];
    const int bp = blockIdx.x;
    const int bc = blockIdx.y;
    const int p0 = bp * 32, c0 = bc * 32;
    const int tx = threadIdx.x & 31, ty = threadIdx.x >> 5;

    for (int r = ty; r < 32; r += 8) {
        const int p = p0 + r;
        tile[r][tx] = (p < NPIX) ? vtmp[(size_t)p * 2048 + c0 + tx] : 0.f;
    }
    __syncthreads();
    for (int r = ty; r < 32; r += 8) {
        const int c = c0 + r;
        const int p = p0 + tx;
        if (p < NPIX) out[(size_t)c * NPIX + p] = tile[tx][r];
    }
}

// ---------------------------------------------------------------------------
// Round-1 fp32 fallback (proven correct) — used only if ws too small
// ---------------------------------------------------------------------------
__launch_bounds__(256, 2)
__global__ void capsconv_fp32(const float* __restrict__ x,
                              const float* __restrict__ Wc,
                              const float* __restrict__ bias,
                              float* __restrict__ outbuf,
                              const int direct_out)
{
    __shared__ float As[KC][BI];
    __shared__ float Bsh[KC][NOC];
    __shared__ float cij[64];
    __shared__ float bijs2[64];
    __shared__ float aTmp2[BB * 64];

    const int t  = threadIdx.x;
    const int tn = t & 15;
    const int tm = t >> 4;
    const int p  = blockIdx.x;
    const int px = p / OWH;
    const int py = p % OWH;
    const int row0 = 2 * px - 2;
    const int col0 = 2 * py - 2;
    const bool interior = (px >= 1 && px <= 63 && py >= 1 && py <= 63);

    float C[8][8];
#pragma unroll
    for (int r = 0; r < 8; ++r)
#pragma unroll
        for (int j = 0; j < 8; ++j) C[r][j] = 0.f;

    float areg[8][4];
    float breg[32];

    auto load_chunk = [&](int kc) {
#pragma unroll
        for (int g = 0; g < 8; ++g) {
            const int L    = g * 256 + t;
            const int bi   = L & 127;
            const int cikw = L >> 7;
            const int ci   = kc * 4 + (cikw >> 2);
            const int kw   = cikw & 3;
            const int row  = row0 + kw;
            const float* src = x + (((size_t)(bi * CIN + ci) * WH + row) * WH + col0);
            if (interior) {
                const float2 v01 = *(const float2*)(src);
                const float2 v23 = *(const float2*)(src + 2);
                areg[g][0] = v01.x; areg[g][1] = v01.y;
                areg[g][2] = v23.x; areg[g][3] = v23.y;
            } else {
#pragma unroll
                for (int kh = 0; kh < 4; ++kh) {
                    const int col = col0 + kh;
                    areg[g][kh] = (row >= 0 && row < WH && col >= 0 && col < WH)
                                      ? src[kh] : 0.f;
                }
            }
        }
        {
            const int oc  = t >> 1;
            const int kk0 = (t & 1) * 32;
            const float* wsrc = Wc + (size_t)oc * KTOT + kc * KC + kk0;
#pragma unroll
            for (int m = 0; m < 32; m += 4) {
                const float4 v = *(const float4*)(wsrc + m);
                breg[m] = v.x; breg[m+1] = v.y; breg[m+2] = v.z; breg[m+3] = v.w;
            }
        }
    };

    load_chunk(0);
    for (int kc = 0; kc < NCHUNK; ++kc) {
        __syncthreads();
#pragma unroll
        for (int g = 0; g < 8; ++g) {
            const int L    = g * 256 + t;
            const int bi   = L & 127;
            const int cikw = L >> 7;
            const int kkb  = cikw * 4;
#pragma unroll
            for (int kh = 0; kh < 4; ++kh) As[kkb + kh][bi] = areg[g][kh];
        }
        {
            const int oc  = t >> 1;
            const int kk0 = (t & 1) * 32;
#pragma unroll
            for (int m = 0; m < 32; ++m) Bsh[kk0 + m][oc] = breg[m];
        }
        __syncthreads();
        if (kc < NCHUNK - 1) load_chunk(kc + 1);
#pragma unroll 4
        for (int k = 0; k < KC; ++k) {
            float af[8], bf[8];
            *(float4*)(af)     = *(const float4*)&As[k][tm * 8];
            *(float4*)(af + 4) = *(const float4*)&As[k][tm * 8 + 4];
            *(float4*)(bf)     = *(const float4*)&Bsh[k][tn * 8];
            *(float4*)(bf + 4) = *(const float4*)&Bsh[k][tn * 8 + 4];
#pragma unroll
            for (int r = 0; r < 8; ++r)
#pragma unroll
                for (int j = 0; j < 8; ++j)
                    C[r][j] = fmaf(af[r], bf[j], C[r][j]);
        }
    }
#pragma unroll
    for (int j = 0; j < 8; ++j) {
        const float bj = bias[tn * 8 + j];
#pragma unroll
        for (int r = 0; r < 8; ++r) C[r][j] += bj;
    }

    const int o = tn >> 1;
    __syncthreads();
    if (t < 64) bijs2[t] = 0.f;

    float vout[8];
    for (int it = 0; it < 3; ++it) {
        __syncthreads();
        if (t < 8) {
            const int oo = t;
            float mx = -1e30f;
#pragma unroll
            for (int i = 0; i < 8; ++i) mx = fmaxf(mx, bijs2[i * 8 + oo]);
            float e[8]; float ssum = 0.f;
#pragma unroll
            for (int i = 0; i < 8; ++i) { e[i] = expf(bijs2[i * 8 + oo] - mx); ssum += e[i]; }
            const float inv = 1.f / ssum;
#pragma unroll
            for (int i = 0; i < 8; ++i) cij[i * 8 + oo] = e[i] * inv;
        }
        __syncthreads();
        float cf[8];
#pragma unroll
        for (int i = 0; i < 8; ++i) cf[i] = cij[i * 8 + o];
        float s[8];
#pragma unroll
        for (int j = 0; j < 8; ++j) {
            float acc = 0.f;
#pragma unroll
            for (int r = 0; r < 8; ++r) acc = fmaf(cf[r], C[r][j], acc);
            s[j] = acc;
        }
        float ssq = 0.f;
#pragma unroll
        for (int j = 0; j < 8; ++j) ssq = fmaf(s[j], s[j], ssq);
        ssq += __shfl_xor(ssq, 1);
        const float scale = ssq / ((1.f + ssq) * sqrtf(ssq));
        if (it == 2) {
#pragma unroll
            for (int j = 0; j < 8; ++j) vout[j] = s[j] * scale;
        } else {
            float ap[8];
#pragma unroll
            for (int r = 0; r < 8; ++r) {
                float acc = 0.f;
#pragma unroll
                for (int j = 0; j < 8; ++j) acc = fmaf(C[r][j], s[j] * scale, acc);
                ap[r] = acc;
            }
#pragma unroll
            for (int r = 0; r < 8; ++r) ap[r] += __shfl_xor(ap[r], 1);
            if ((tn & 1) == 0) {
#pragma unroll
                for (int r = 0; r < 8; ++r) aTmp2[tm * 64 + r * 8 + o] = ap[r];
            }
            __syncthreads();
            if (t < 64) {
                float acc = 0.f;
#pragma unroll
                for (int b = 0; b < BB; ++b) acc += aTmp2[b * 64 + t];
                bijs2[t] += acc * (1.f / 16.f);
            }
        }
    }
    if (direct_out) {
#pragma unroll
        for (int j = 0; j < 8; ++j)
            outbuf[(size_t)(tm * NOC + tn * 8 + j) * NPIX + p] = vout[j];
    } else {
        float4* dst = (float4*)(outbuf + (size_t)p * 2048 + tm * NOC + tn * 8);
        dst[0] = make_float4(vout[0], vout[1], vout[2], vout[3]);
        dst[1] = make_float4(vout[4], vout[5], vout[6], vout[7]);
    }
}

extern "C" void kernel_launch(void* const* d_in, const int* in_sizes, int n_in,
                              void* d_out, int out_size, void* d_ws, size_t ws_size,
                              hipStream_t stream)
{
    const float* x    = (const float*)d_in[0];
    const float* Wc   = (const float*)d_in[1];
    const float* bias = (const float*)d_in[2];
    float* out        = (float*)d_out;

    const size_t VT_BYTES = (size_t)NPIX * 2048 * sizeof(float);   // 34,611,200
    const size_t WB_OFF   = VT_BYTES;
    const size_t XB_OFF   = WB_OFF + 65536;
    const size_t TOTAL    = XB_OFF + (size_t)BI * CIN * WH * WH * 2;  // 101,785,600

    if (ws_size >= TOTAL) {
        float*   vtmp = (float*)d_ws;
        ushortT* Wbf  = (ushortT*)((char*)d_ws + WB_OFF);
        ushortT* xbf  = (ushortT*)((char*)d_ws + XB_OFF);

        cvt_x_kernel<<<8192, 256, 0, stream>>>((const float4*)x, (ushort4*)xbf,
                                               BI * CIN * WH * WH / 4);
        prep_w_kernel<<<128, 256, 0, stream>>>(Wc, Wbf);
        capsconv_mfma<<<529 * 8, 512, 0, stream>>>(xbf, Wbf, bias, vtmp, 0);
        dim3 g((NPIX + 31) / 32, 2048 / 32);
        transpose_kernel<<<g, 256, 0, stream>>>(vtmp, out);
    } else if (ws_size >= VT_BYTES) {
        float* vtmp = (float*)d_ws;
        capsconv_fp32<<<NPIX, 256, 0, stream>>>(x, Wc, bias, vtmp, 0);
        dim3 g((NPIX + 31) / 32, 2048 / 32);
        transpose_kernel<<<g, 256, 0, stream>>>(vtmp, out);
    } else {
        capsconv_fp32<<<NPIX, 256, 0, stream>>>(x, Wc, bias, out, 1);
    }
}

// Round 3
// 418.861 us; speedup vs baseline: 1.9428x; 1.9428x over previous
//
#include <hip/hip_runtime.h>
#include <math.h>

// Problem constants
#define BB   16      // batch
#define IC   8       // in capsules
#define BI   128     // BB*IC
#define CIN  16      // conv in channels
#define WH   128     // input spatial
#define OWH  65      // output spatial (stride 2, pad 2, k 4)
#define NPIX (OWH*OWH)   // 4225
#define OC   8       // out capsules
#define COUT 16      // out channel per capsule
#define NOC  128     // OC*Cout
#define KTOT 256     // CIN*4*4
#define KC   64      // (fp32 fallback chunk)
#define NCHUNK 4
#define S_TOTAL (CIN*WH*WH)   // 262144 (per-bi s = (ci,row,col) extent)

// MFMA kernel: K chunked by 32 (one mfma-K per chunk), 8 chunks
#define NCHM 8

typedef unsigned short ushortT;
typedef __bf16 bf16x8 __attribute__((ext_vector_type(8)));
typedef float  f32x4  __attribute__((ext_vector_type(4)));

__device__ __forceinline__ ushortT f2bf(float f) {
    unsigned u = __float_as_uint(f);
    unsigned r = (u + 0x7fffu + ((u >> 16) & 1u)) >> 16;
    return (ushortT)r;
}

// ---------------------------------------------------------------------------
// Pre-pass 1: x fp32 [bi][ci][row][col] -> bf16 TRANSPOSED xbfT[s][bi],
// s = (ci*WH+row)*WH+col (bi innermost => GEMM A-staging is coalesced).
// LDS-tiled: block = 64 consecutive s x all 128 bi.
// ---------------------------------------------------------------------------
__global__ void cvtT_kernel(const float* __restrict__ x,
                            ushortT* __restrict__ xbfT)
{
    __shared__ ushortT tile[64 * 136];   // [sIdx][bi], stride 136, XOR-swizzled
    const int t  = threadIdx.x;          // 0..255
    const int s0 = blockIdx.x * 64;      // 4096 blocks

    // load: 2048 float4 (128 bi x 16 s-quads); 8 per thread
#pragma unroll
    for (int k = 0; k < 8; ++k) {
        const int j  = t + k * 256;
        const int bi = j >> 4, s4 = j & 15;
        const float4 v = *(const float4*)(x + (size_t)bi * S_TOTAL + s0 + s4 * 4);
        const int si = s4 * 4;
        tile[(si    ) * 136 + (bi ^ (((si    ) & 15) << 3))] = f2bf(v.x);
        tile[(si + 1) * 136 + (bi ^ (((si + 1) & 15) << 3))] = f2bf(v.y);
        tile[(si + 2) * 136 + (bi ^ (((si + 2) & 15) << 3))] = f2bf(v.z);
        tile[(si + 3) * 136 + (bi ^ (((si + 3) & 15) << 3))] = f2bf(v.w);
    }
    __syncthreads();
    // store: 1024 x 16B (64 s x 16 bi-octets); 4 per thread, fully coalesced
#pragma unroll
    for (int k = 0; k < 4; ++k) {
        const int j  = t + k * 256;
        const int sI = j >> 4, g = j & 15;
        const uint4 val = *(const uint4*)&tile[sI * 136 + ((g ^ (sI & 15)) << 3)];
        *(uint4*)(xbfT + (size_t)(s0 + sI) * 128 + g * 8) = val;
    }
}

// ---------------------------------------------------------------------------
// Pre-pass 2: W fp32 [oc][k] -> bf16 prepacked fragment image:
//   Wbf[(kpg*128+oc)*8 + j]   (k = kpg*8 + j, kpg = 0..31)
// ---------------------------------------------------------------------------
__global__ void prep_w_kernel(const float* __restrict__ W,
                              ushortT* __restrict__ Wbf)
{
    int idx = blockIdx.x * 256 + threadIdx.x;   // 32768 total
    int oc = idx >> 8, k = idx & 255;
    int kpg = k >> 3, j = k & 7;
    Wbf[((size_t)kpg * 128 + oc) * 8 + j] = f2bf(W[idx]);
}

// ---------------------------------------------------------------------------
// Fused MFMA kernel, 512 threads (8 waves). Wave w owns a 64x32 C quadrant:
// rows [64*(w>>2), +64) x cols [32*(w&3), +32) as 4x2 tiles of 16x16.
//
// v4: r0 structure (same LDS A/B image, ds_read_b128 fragments, 1 barrier
// per chunk, routing unchanged) but A staged from TRANSPOSED xbfT:
//  - thread t: g=t&15 (bi octet), sI=t>>4 -> (cihalf=sI>>4,rowl=(sI>>2)&3,col=sI&3)
//    loads ONE uint4 = 8 bi of s=((2kc+cihalf)*WH+row0+rowl)*WH+col0+col.
//    Wave reads 1KB contiguous (vs r0's 64 scattered lines per instr).
//  - LDS transpose via 8x ds_write_b16 with XOR swizzle
//    byte' = byte ^ (((byte>>7)&7)<<4); fragment reads apply same involution.
//    Write conflicts ~4-way (free-ish); reads conflict-free.
//  - LDS image CONTENT is bit-identical to r0's proven layout:
//    As[(kpg*128+bi)*8 + j], kpg=cihalf*2+(rowl>>1), j=(rowl&1)*4+col.
// C/D: col=lane&15 -> oc-col c, row=4*quad+reg -> (b,i). direct_out write.
// ---------------------------------------------------------------------------
__launch_bounds__(512, 4)
__global__ void capsconv_mfma(const ushortT* __restrict__ xbfT,
                              const ushortT* __restrict__ Wbf,
                              const float* __restrict__ bias,
                              float* __restrict__ outbuf,
                              const int direct_out)
{
    __shared__ __align__(16) ushortT As[2][4 * 128 * 8];   // 2 x 8 KB
    __shared__ __align__(16) ushortT Bs[2][4 * 128 * 8];   // 2 x 8 KB
    __shared__ float cijs[64];       // [o][i]
    __shared__ float bijs[64];       // [o][i] (wave 0 only)
    __shared__ float aTmp[16 * 64];  // [b][o*8+i]

    const int t  = threadIdx.x;      // 0..511
    const int g8 = blockIdx.x;
    int p = (g8 & 7) * 529 + (g8 >> 3);     // XCD-contiguous pixel strips
    if (p >= NPIX) return;

    const int w  = t >> 6;       // wave id 0..7
    const int ln = t & 63;
    const int q  = ln >> 4;      // quad
    const int cL = ln & 15;      // lane col (c within tile)
    const int h  = q & 1;        // i-half
    const int mrow_base = 64 * (w >> 2);   // 0 or 64
    const int ncol_base = 32 * (w & 3);    // 0,32,64,96

    const int px = p / OWH;
    const int py = p % OWH;
    const int row0 = 2 * px - 2;
    const int col0 = 2 * py - 2;

    f32x4 acc[4][2];
#pragma unroll
    for (int mt = 0; mt < 4; ++mt)
#pragma unroll
        for (int nt = 0; nt < 2; ++nt) acc[mt][nt] = (f32x4){0.f, 0.f, 0.f, 0.f};

    // ---- A staging map (per thread, chunk-invariant except source ci) ----
    const int g     = t & 15;        // bi octet
    const int sI    = t >> 4;        // 0..31
    const int colw  = sI & 3;
    const int rowl  = (sI >> 2) & 3;
    const int cih   = sI >> 4;       // 0..1
    const int srow  = row0 + rowl;
    const int scol  = col0 + colw;
    const bool ok   = (srow >= 0 && srow < WH && scol >= 0 && scol < WH);
    const size_t aoff0 = ok
        ? ((size_t)((cih * WH + srow) * WH + scol) * 128 + g * 8)
        : 0;
    // LDS dest (bytes within As[buf]); bits 4-6 of wbase are zero.
    const int kpg   = cih * 2 + (rowl >> 1);
    const int jj    = (rowl & 1) * 4 + colw;
    const int wbase = (kpg * 128 + g * 8) * 16 + jj * 2;
    const int gk7   = g & 7;

    // fragment read byte offsets (swizzled), chunk-invariant
    int aRd[4];
#pragma unroll
    for (int mt = 0; mt < 4; ++mt) {
        const int by = (q * 128 + mrow_base + mt * 16 + cL) * 16;
        aRd[mt] = by ^ (((by >> 7) & 7) << 4);
    }

    uint4 aR;   // A staging value (8 bi-values of one s)
    uint4 bR;   // B staging value

    auto loadA = [&](int kc) {
        aR = make_uint4(0u, 0u, 0u, 0u);
        if (ok) aR = *(const uint4*)(xbfT + aoff0 + (size_t)kc * (2 * WH * WH * 128));
    };
    auto loadB = [&](int kc) {
        bR = ((const uint4*)Wbf)[kc * 512 + t];
    };
    auto storeAB = [&](int buf) {
        char* ab = (char*)&As[buf][0];
        const ushortT* av = (const ushortT*)&aR;
#pragma unroll
        for (int c = 0; c < 8; ++c)
            *(ushortT*)(ab + wbase + ((c ^ gk7) << 4)) = av[c];
        ((uint4*)Bs[buf])[t] = bR;
    };

    loadA(0); loadB(0);
    storeAB(0);

    for (int kc = 0; kc < NCHM; ++kc) {
        __syncthreads();   // buf[kc&1] writes visible; old reads of other buf done
        if (kc < NCHM - 1) { loadA(kc + 1); loadB(kc + 1); }   // latency overlapped

        {
            const int buf = kc & 1;
            const char* abase = (const char*)&As[buf][0];
            bf16x8 af[4], bfr[2];
#pragma unroll
            for (int mt = 0; mt < 4; ++mt)
                af[mt] = *(const bf16x8*)(abase + aRd[mt]);
#pragma unroll
            for (int nt = 0; nt < 2; ++nt)
                bfr[nt] = *(const bf16x8*)&Bs[buf][(q * 128 + ncol_base + nt * 16 + cL) * 8];
#pragma unroll
            for (int mt = 0; mt < 4; ++mt)
#pragma unroll
                for (int nt = 0; nt < 2; ++nt)
                    acc[mt][nt] = __builtin_amdgcn_mfma_f32_16x16x32_bf16(
                        af[mt], bfr[nt], acc[mt][nt], 0, 0, 0);
        }

        if (kc < NCHM - 1) storeAB((kc + 1) & 1);   // vmcnt wait lands here
    }

    // bias epilogue
#pragma unroll
    for (int nt = 0; nt < 2; ++nt) {
        const float bv = bias[ncol_base + nt * 16 + cL];
#pragma unroll
        for (int mt = 0; mt < 4; ++mt) acc[mt][nt] += bv;
    }

    // ---------------- dynamic routing (3 iters) ----------------
    // iter 0: b_ij = 0 -> c_ij = 1/8 exactly (no softmax needed).
    for (int it = 0; it < 3; ++it) {
        float4 cf4[2];
        if (it == 0) {
#pragma unroll
            for (int nt = 0; nt < 2; ++nt)
                cf4[nt] = make_float4(0.125f, 0.125f, 0.125f, 0.125f);
        } else {
#pragma unroll
            for (int nt = 0; nt < 2; ++nt)
                cf4[nt] = *(const float4*)&cijs[(2 * (w & 3) + nt) * 8 + 4 * h];
        }

#pragma unroll
        for (int mt = 0; mt < 4; ++mt) {
            const int b = 8 * (w >> 2) + 2 * mt + (q >> 1);
#pragma unroll
            for (int nt = 0; nt < 2; ++nt) {
                const int o = 2 * (w & 3) + nt;
                const float4 cf = cf4[nt];
                float sp = cf.x * acc[mt][nt][0] + cf.y * acc[mt][nt][1]
                         + cf.z * acc[mt][nt][2] + cf.w * acc[mt][nt][3];
                float s = sp + __shfl_xor(sp, 16);
                float ssq = s * s;
#pragma unroll
                for (int d = 1; d < 16; d <<= 1) ssq += __shfl_xor(ssq, d);
                const float scale = sqrtf(ssq) * __builtin_amdgcn_rcpf(1.f + ssq);
                const float vj = s * scale;

                if (it == 2) {
                    if (q == 0 || q == 2) {
                        if (direct_out)
                            outbuf[(size_t)(b * NOC + o * 16 + cL) * NPIX + p] = vj;
                        else
                            outbuf[(size_t)p * 2048 + b * NOC + o * 16 + cL] = vj;
                    }
                } else {
                    f32x4 ap = acc[mt][nt] * vj;
#pragma unroll
                    for (int d = 1; d < 16; d <<= 1) {
                        ap[0] += __shfl_xor(ap[0], d);
                        ap[1] += __shfl_xor(ap[1], d);
                        ap[2] += __shfl_xor(ap[2], d);
                        ap[3] += __shfl_xor(ap[3], d);
                    }
                    if (cL == 0) {
                        float* dst = &aTmp[b * 64 + o * 8 + 4 * h];
                        dst[0] = ap[0]; dst[1] = ap[1]; dst[2] = ap[2]; dst[3] = ap[3];
                    }
                }
            }
        }
        if (it < 2) {
            __syncthreads();   // aTmp writes visible
            if (t < 64) {
                float sum = 0.f;
#pragma unroll
                for (int b = 0; b < BB; ++b) sum += aTmp[b * 64 + t];
                float bij = (it == 0 ? 0.f : bijs[t]) + sum * (1.f / 16.f);
                bijs[t] = bij;
                float mx = bij;
                mx = fmaxf(mx, __shfl_xor(mx, 1));
                mx = fmaxf(mx, __shfl_xor(mx, 2));
                mx = fmaxf(mx, __shfl_xor(mx, 4));
                float e = __expf(bij - mx);
                float se = e;
                se += __shfl_xor(se, 1);
                se += __shfl_xor(se, 2);
                se += __shfl_xor(se, 4);
                cijs[t] = e * __builtin_amdgcn_rcpf(se);
            }
            __syncthreads();
        }
    }
}

// ---------------------------------------------------------------------------
// [pixel][boc] -> [boc][pixel] tiled transpose (fallback path only)
// ---------------------------------------------------------------------------
__global__ void transpose_kernel(const float* __restrict__ vtmp,
                                 float* __restrict__ out)
{
    __shared__ float tile[32][33];
    const int bp = blockIdx.x;
    const int bc = blockIdx.y;
    const int p0 = bp * 32, c0 = bc * 32;
    const int tx = threadIdx.x & 31, ty = threadIdx.x >> 5;

    for (int r = ty; r < 32; r += 8) {
        const int p = p0 + r;
        tile[r][tx] = (p < NPIX) ? vtmp[(size_t)p * 2048 + c0 + tx] : 0.f;
    }
    __syncthreads();
    for (int r = ty; r < 32; r += 8) {
        const int c = c0 + r;
        const int p = p0 + tx;
        if (p < NPIX) out[(size_t)c * NPIX + p] = tile[tx][r];
    }
}

// ---------------------------------------------------------------------------
// Round-1 fp32 fallback (proven correct) — used only if ws too small
// ---------------------------------------------------------------------------
__launch_bounds__(256, 2)
__global__ void capsconv_fp32(const float* __restrict__ x,
                              const float* __restrict__ Wc,
                              const float* __restrict__ bias,
                              float* __restrict__ outbuf,
                              const int direct_out)
{
    __shared__ float As[KC][BI];
    __shared__ float Bsh[KC][NOC];
    __shared__ float cij[64];
    __shared__ float bijs2[64];
    __shared__ float aTmp2[BB * 64];

    const int t  = threadIdx.x;
    const int tn = t & 15;
    const int tm = t >> 4;
    const int p  = blockIdx.x;
    const int px = p / OWH;
    const int py = p % OWH;
    const int row0 = 2 * px - 2;
    const int col0 = 2 * py - 2;
    const bool interior = (px >= 1 && px <= 63 && py >= 1 && py <= 63);

    float C[8][8];
#pragma unroll
    for (int r = 0; r < 8; ++r)
#pragma unroll
        for (int j = 0; j < 8; ++j) C[r][j] = 0.f;

    float areg[8][4];
    float breg[32];

    auto load_chunk = [&](int kc) {
#pragma unroll
        for (int g = 0; g < 8; ++g) {
            const int L    = g * 256 + t;
            const int bi   = L & 127;
            const int cikw = L >> 7;
            const int ci   = kc * 4 + (cikw >> 2);
            const int kw   = cikw & 3;
            const int row  = row0 + kw;
            const float* src = x + (((size_t)(bi * CIN + ci) * WH + row) * WH + col0);
            if (interior) {
                const float2 v01 = *(const float2*)(src);
                const float2 v23 = *(const float2*)(src + 2);
                areg[g][0] = v01.x; areg[g][1] = v01.y;
                areg[g][2] = v23.x; areg[g][3] = v23.y;
            } else {
#pragma unroll
                for (int kh = 0; kh < 4; ++kh) {
                    const int col = col0 + kh;
                    areg[g][kh] = (row >= 0 && row < WH && col >= 0 && col < WH)
                                      ? src[kh] : 0.f;
                }
            }
        }
        {
            const int oc  = t >> 1;
            const int kk0 = (t & 1) * 32;
            const float* wsrc = Wc + (size_t)oc * KTOT + kc * KC + kk0;
#pragma unroll
            for (int m = 0; m < 32; m += 4) {
                const float4 v = *(const float4*)(wsrc + m);
                breg[m] = v.x; breg[m+1] = v.y; breg[m+2] = v.z; breg[m+3] = v.w;
            }
        }
    };

    load_chunk(0);
    for (int kc = 0; kc < NCHUNK; ++kc) {
        __syncthreads();
#pragma unroll
        for (int g = 0; g < 8; ++g) {
            const int L    = g * 256 + t;
            const int bi   = L & 127;
            const int cikw = L >> 7;
            const int kkb  = cikw * 4;
#pragma unroll
            for (int kh = 0; kh < 4; ++kh) As[kkb + kh][bi] = areg[g][kh];
        }
        {
            const int oc  = t >> 1;
            const int kk0 = (t & 1) * 32;
#pragma unroll
            for (int m = 0; m < 32; ++m) Bsh[kk0 + m][oc] = breg[m];
        }
        __syncthreads();
        if (kc < NCHUNK - 1) load_chunk(kc + 1);
#pragma unroll 4
        for (int k = 0; k < KC; ++k) {
            float af[8], bf[8];
            *(float4*)(af)     = *(const float4*)&As[k][tm * 8];
            *(float4*)(af + 4) = *(const float4*)&As[k][tm * 8 + 4];
            *(float4*)(bf)     = *(const float4*)&Bsh[k][tn * 8];
            *(float4*)(bf + 4) = *(const float4*)&Bsh[k][tn * 8 + 4];
#pragma unroll
            for (int r = 0; r < 8; ++r)
#pragma unroll
                for (int j = 0; j < 8; ++j)
                    C[r][j] = fmaf(af[r], bf[j], C[r][j]);
        }
    }
#pragma unroll
    for (int j = 0; j < 8; ++j) {
        const float bj = bias[tn * 8 + j];
#pragma unroll
        for (int r = 0; r < 8; ++r) C[r][j] += bj;
    }

    const int o = tn >> 1;
    __syncthreads();
    if (t < 64) bijs2[t] = 0.f;

    float vout[8];
    for (int it = 0; it < 3; ++it) {
        __syncthreads();
        if (t < 8) {
            const int oo = t;
            float mx = -1e30f;
#pragma unroll
            for (int i = 0; i < 8; ++i) mx = fmaxf(mx, bijs2[i * 8 + oo]);
            float e[8]; float ssum = 0.f;
#pragma unroll
            for (int i = 0; i < 8; ++i) { e[i] = expf(bijs2[i * 8 + oo] - mx); ssum += e[i]; }
            const float inv = 1.f / ssum;
#pragma unroll
            for (int i = 0; i < 8; ++i) cij[i * 8 + oo] = e[i] * inv;
        }
        __syncthreads();
        float cf[8];
#pragma unroll
        for (int i = 0; i < 8; ++i) cf[i] = cij[i * 8 + o];
        float s[8];
#pragma unroll
        for (int j = 0; j < 8; ++j) {
            float acc = 0.f;
#pragma unroll
            for (int r = 0; r < 8; ++r) acc = fmaf(cf[r], C[r][j], acc);
            s[j] = acc;
        }
        float ssq = 0.f;
#pragma unroll
        for (int j = 0; j < 8; ++j) ssq = fmaf(s[j], s[j], ssq);
        ssq += __shfl_xor(ssq, 1);
        const float scale = ssq / ((1.f + ssq) * sqrtf(ssq));
        if (it == 2) {
#pragma unroll
            for (int j = 0; j < 8; ++j) vout[j] = s[j] * scale;
        } else {
            float ap[8];
#pragma unroll
            for (int r = 0; r < 8; ++r) {
                float acc = 0.f;
#pragma unroll
                for (int j = 0; j < 8; ++j) acc = fmaf(C[r][j], s[j] * scale, acc);
                ap[r] = acc;
            }
#pragma unroll
            for (int r = 0; r < 8; ++r) ap[r] += __shfl_xor(ap[r], 1);
            if ((tn & 1) == 0) {
#pragma unroll
                for (int r = 0; r < 8; ++r) aTmp2[tm * 64 + r * 8 + o] = ap[r];
            }
            __syncthreads();
            if (t < 64) {
                float acc = 0.f;
#pragma unroll
                for (int b = 0; b < BB; ++b) acc += aTmp2[b * 64 + t];
                bijs2[t] += acc * (1.f / 16.f);
            }
        }
    }
    if (direct_out) {
#pragma unroll
        for (int j = 0; j < 8; ++j)
            outbuf[(size_t)(tm * NOC + tn * 8 + j) * NPIX + p] = vout[j];
    } else {
        float4* dst = (float4*)(outbuf + (size_t)p * 2048 + tm * NOC + tn * 8);
        dst[0] = make_float4(vout[0], vout[1], vout[2], vout[3]);
        dst[1] = make_float4(vout[4], vout[5], vout[6], vout[7]);
    }
}

extern "C" void kernel_launch(void* const* d_in, const int* in_sizes, int n_in,
                              void* d_out, int out_size, void* d_ws, size_t ws_size,
                              hipStream_t stream)
{
    const float* x    = (const float*)d_in[0];
    const float* Wc   = (const float*)d_in[1];
    const float* bias = (const float*)d_in[2];
    float* out        = (float*)d_out;

    const size_t VT_BYTES = (size_t)NPIX * 2048 * sizeof(float);   // 34,611,200
    const size_t WB_OFF   = VT_BYTES;
    const size_t XB_OFF   = WB_OFF + 65536;
    const size_t TOTAL    = XB_OFF + (size_t)BI * CIN * WH * WH * 2;  // 101,785,600

    if (ws_size >= TOTAL) {
        ushortT* Wbf  = (ushortT*)((char*)d_ws + WB_OFF);
        ushortT* xbfT = (ushortT*)((char*)d_ws + XB_OFF);

        cvtT_kernel<<<S_TOTAL / 64, 256, 0, stream>>>(x, xbfT);
        prep_w_kernel<<<128, 256, 0, stream>>>(Wc, Wbf);
        capsconv_mfma<<<529 * 8, 512, 0, stream>>>(xbfT, Wbf, bias, out, 1);
    } else if (ws_size >= VT_BYTES) {
        float* vtmp = (float*)d_ws;
        capsconv_fp32<<<NPIX, 256, 0, stream>>>(x, Wc, bias, vtmp, 0);
        dim3 g((NPIX + 31) / 32, 2048 / 32);
        transpose_kernel<<<g, 256, 0, stream>>>(vtmp, out);
    } else {
        capsconv_fp32<<<NPIX, 256, 0, stream>>>(x, Wc, bias, out, 1);
    }
}

// Round 4
// 411.483 us; speedup vs baseline: 1.9776x; 1.0179x over previous
//
#include <hip/hip_runtime.h>
#include <math.h>

// Problem constants
#define BB   16      // batch
#define IC   8       // in capsules
#define BI   128     // BB*IC
#define CIN  16      // conv in channels
#define WH   128     // input spatial
#define OWH  65      // output spatial (stride 2, pad 2, k 4)
#define NPIX (OWH*OWH)   // 4225
#define OC   8       // out capsules
#define COUT 16      // out channel per capsule
#define NOC  128     // OC*Cout
#define KTOT 256     // CIN*4*4
#define KC   64      // (fp32 fallback chunk)
#define NCHUNK 4
#define S_TOTAL (CIN*WH*WH)   // 262144 (per-bi s = (ci,row,col) extent)

// MFMA kernel: K chunked by 32 (one mfma-K per chunk), 8 chunks
#define NCHM 8

typedef unsigned short ushortT;
typedef __bf16 bf16x8 __attribute__((ext_vector_type(8)));
typedef float  f32x4  __attribute__((ext_vector_type(4)));

__device__ __forceinline__ ushortT f2bf(float f) {
    unsigned u = __float_as_uint(f);
    unsigned r = (u + 0x7fffu + ((u >> 16) & 1u)) >> 16;
    return (ushortT)r;
}

// ---------------------------------------------------------------------------
// Pre-pass 1: x fp32 [bi][ci][row][col] -> bf16 TRANSPOSED xbfT[s][bi],
// s = (ci*WH+row)*WH+col (bi innermost => GEMM A-staging is coalesced).
// LDS-tiled: block = 64 consecutive s x all 128 bi.
// ---------------------------------------------------------------------------
__global__ void cvtT_kernel(const float* __restrict__ x,
                            ushortT* __restrict__ xbfT)
{
    __shared__ ushortT tile[64 * 136];   // [sIdx][bi], stride 136, XOR-swizzled
    const int t  = threadIdx.x;          // 0..255
    const int s0 = blockIdx.x * 64;      // 4096 blocks

    // load: 2048 float4 (128 bi x 16 s-quads); 8 per thread
#pragma unroll
    for (int k = 0; k < 8; ++k) {
        const int j  = t + k * 256;
        const int bi = j >> 4, s4 = j & 15;
        const float4 v = *(const float4*)(x + (size_t)bi * S_TOTAL + s0 + s4 * 4);
        const int si = s4 * 4;
        tile[(si    ) * 136 + (bi ^ (((si    ) & 15) << 3))] = f2bf(v.x);
        tile[(si + 1) * 136 + (bi ^ (((si + 1) & 15) << 3))] = f2bf(v.y);
        tile[(si + 2) * 136 + (bi ^ (((si + 2) & 15) << 3))] = f2bf(v.z);
        tile[(si + 3) * 136 + (bi ^ (((si + 3) & 15) << 3))] = f2bf(v.w);
    }
    __syncthreads();
    // store: 1024 x 16B (64 s x 16 bi-octets); 4 per thread, fully coalesced
#pragma unroll
    for (int k = 0; k < 4; ++k) {
        const int j  = t + k * 256;
        const int sI = j >> 4, g = j & 15;
        const uint4 val = *(const uint4*)&tile[sI * 136 + ((g ^ (sI & 15)) << 3)];
        *(uint4*)(xbfT + (size_t)(s0 + sI) * 128 + g * 8) = val;
    }
}

// ---------------------------------------------------------------------------
// Pre-pass 2: W fp32 [oc][k] -> bf16 prepacked fragment image:
//   Wbf[(kpg*128+oc)*8 + j]   (k = kpg*8 + j, kpg = 0..31)
// ---------------------------------------------------------------------------
__global__ void prep_w_kernel(const float* __restrict__ W,
                              ushortT* __restrict__ Wbf)
{
    int idx = blockIdx.x * 256 + threadIdx.x;   // 32768 total
    int oc = idx >> 8, k = idx & 255;
    int kpg = k >> 3, j = k & 7;
    Wbf[((size_t)kpg * 128 + oc) * 8 + j] = f2bf(W[idx]);
}

// ---------------------------------------------------------------------------
// Fused MFMA kernel, 512 threads (8 waves). Wave w owns a 64x32 C quadrant:
// rows [64*(w>>2), +64) x cols [32*(w&3), +32) as 4x2 tiles of 16x16.
//
// v5 (from v4, which passed on HW):
//  - B fragments read DIRECTLY from global Wbf (L2-resident 64KB; the old
//    Bs[buf][i] was bit-identical to Wbf[kc*4096+i], so indices carry over).
//    No barrier dependency -> compiler hoists B loads across chunks.
//  - A LDS ring deepened to 3 bufs: load for chunk kc+3 issued at kc, its
//    ds-store (vmcnt wait) at kc+2 -> ~2 chunk periods of latency cover.
//    A image per buf is bit-identical to v4's proven swizzled layout:
//    nominal byte = (kpg*128+bi)*16 + j*2, XOR ((byte>>7)&7)<<4 on both sides.
// C/D: col=lane&15 -> oc-col c, row=4*quad+reg -> (b,i). direct_out write.
// ---------------------------------------------------------------------------
__launch_bounds__(512, 4)
__global__ void capsconv_mfma(const ushortT* __restrict__ xbfT,
                              const ushortT* __restrict__ Wbf,
                              const float* __restrict__ bias,
                              float* __restrict__ outbuf,
                              const int direct_out)
{
    __shared__ __align__(16) ushortT As[3][4 * 128 * 8];   // 3 x 8 KB ring
    __shared__ float cijs[64];       // [o][i]
    __shared__ float bijs[64];       // [o][i] (wave 0 only)
    __shared__ float aTmp[16 * 64];  // [b][o*8+i]

    const int t  = threadIdx.x;      // 0..511
    const int g8 = blockIdx.x;
    int p = (g8 & 7) * 529 + (g8 >> 3);     // XCD-contiguous pixel strips
    if (p >= NPIX) return;

    const int w  = t >> 6;       // wave id 0..7
    const int ln = t & 63;
    const int q  = ln >> 4;      // quad
    const int cL = ln & 15;      // lane col (c within tile)
    const int h  = q & 1;        // i-half
    const int mrow_base = 64 * (w >> 2);   // 0 or 64
    const int ncol_base = 32 * (w & 3);    // 0,32,64,96

    const int px = p / OWH;
    const int py = p % OWH;
    const int row0 = 2 * px - 2;
    const int col0 = 2 * py - 2;

    f32x4 acc[4][2];
#pragma unroll
    for (int mt = 0; mt < 4; ++mt)
#pragma unroll
        for (int nt = 0; nt < 2; ++nt) acc[mt][nt] = (f32x4){0.f, 0.f, 0.f, 0.f};

    // ---- A staging map (per thread, chunk-invariant except source ci) ----
    const int g     = t & 15;        // bi octet
    const int sI    = t >> 4;        // 0..31
    const int colw  = sI & 3;
    const int rowl  = (sI >> 2) & 3;
    const int cih   = sI >> 4;       // 0..1
    const int srow  = row0 + rowl;
    const int scol  = col0 + colw;
    const bool ok   = (srow >= 0 && srow < WH && scol >= 0 && scol < WH);
    const size_t aoff0 = ok
        ? ((size_t)((cih * WH + srow) * WH + scol) * 128 + g * 8)
        : 0;
    // LDS dest (bytes within As[buf]); bits 4-6 of wbase are zero.
    const int kpg   = cih * 2 + (rowl >> 1);
    const int jj    = (rowl & 1) * 4 + colw;
    const int wbase = (kpg * 128 + g * 8) * 16 + jj * 2;
    const int gk7   = g & 7;

    // fragment read byte offsets (swizzled), chunk-invariant
    int aRd[4];
#pragma unroll
    for (int mt = 0; mt < 4; ++mt) {
        const int by = (q * 128 + mrow_base + mt * 16 + cL) * 16;
        aRd[mt] = by ^ (((by >> 7) & 7) << 4);
    }

    uint4 aR[2];   // pending A loads (2 in flight)

    auto loadA = [&](uint4& r, int kc) {
        r = make_uint4(0u, 0u, 0u, 0u);
        if (ok) r = *(const uint4*)(xbfT + aoff0 + (size_t)kc * (2 * WH * WH * 128));
    };
    auto storeA = [&](int buf, const uint4& r) {
        char* ab = (char*)&As[buf][0];
        const ushortT* av = (const ushortT*)&r;
#pragma unroll
        for (int c = 0; c < 8; ++c)
            *(ushortT*)(ab + wbase + ((c ^ gk7) << 4)) = av[c];
    };

    // prologue: chunks 0,1 in flight; store 0; load 2 into freed slot
    loadA(aR[0], 0);
    loadA(aR[1], 1);
    storeA(0, aR[0]);          // vmcnt wait for chunk-0 load lands here
    loadA(aR[0], 2);
    __syncthreads();           // buf0 visible

#pragma unroll
    for (int kc = 0; kc < NCHM; ++kc) {
        const int buf = kc % 3;
        {
            const char* abase = (const char*)&As[buf][0];
            bf16x8 af[4], bfr[2];
#pragma unroll
            for (int mt = 0; mt < 4; ++mt)
                af[mt] = *(const bf16x8*)(abase + aRd[mt]);
            // B direct from global (L2-hot, no barrier dependency)
            const ushortT* bsrc = Wbf + kc * 4096 + (q * 128 + ncol_base + cL) * 8;
            bfr[0] = *(const bf16x8*)(bsrc);
            bfr[1] = *(const bf16x8*)(bsrc + 128);
#pragma unroll
            for (int mt = 0; mt < 4; ++mt)
#pragma unroll
                for (int nt = 0; nt < 2; ++nt)
                    acc[mt][nt] = __builtin_amdgcn_mfma_f32_16x16x32_bf16(
                        af[mt], bfr[nt], acc[mt][nt], 0, 0, 0);
        }
        // ring maintenance: store chunk kc+1 (loaded 2 iters ago), issue kc+3
        if (kc + 1 < NCHM) storeA((kc + 1) % 3, aR[(kc + 1) & 1]);
        if (kc + 3 < NCHM) loadA(aR[(kc + 3) & 1], kc + 3);
        __syncthreads();
    }

    // bias epilogue
#pragma unroll
    for (int nt = 0; nt < 2; ++nt) {
        const float bv = bias[ncol_base + nt * 16 + cL];
#pragma unroll
        for (int mt = 0; mt < 4; ++mt) acc[mt][nt] += bv;
    }

    // ---------------- dynamic routing (3 iters) ----------------
    // iter 0: b_ij = 0 -> c_ij = 1/8 exactly (no softmax needed).
    for (int it = 0; it < 3; ++it) {
        float4 cf4[2];
        if (it == 0) {
#pragma unroll
            for (int nt = 0; nt < 2; ++nt)
                cf4[nt] = make_float4(0.125f, 0.125f, 0.125f, 0.125f);
        } else {
#pragma unroll
            for (int nt = 0; nt < 2; ++nt)
                cf4[nt] = *(const float4*)&cijs[(2 * (w & 3) + nt) * 8 + 4 * h];
        }

#pragma unroll
        for (int mt = 0; mt < 4; ++mt) {
            const int b = 8 * (w >> 2) + 2 * mt + (q >> 1);
#pragma unroll
            for (int nt = 0; nt < 2; ++nt) {
                const int o = 2 * (w & 3) + nt;
                const float4 cf = cf4[nt];
                float sp = cf.x * acc[mt][nt][0] + cf.y * acc[mt][nt][1]
                         + cf.z * acc[mt][nt][2] + cf.w * acc[mt][nt][3];
                float s = sp + __shfl_xor(sp, 16);
                float ssq = s * s;
#pragma unroll
                for (int d = 1; d < 16; d <<= 1) ssq += __shfl_xor(ssq, d);
                const float scale = sqrtf(ssq) * __builtin_amdgcn_rcpf(1.f + ssq);
                const float vj = s * scale;

                if (it == 2) {
                    if (q == 0 || q == 2) {
                        if (direct_out)
                            outbuf[(size_t)(b * NOC + o * 16 + cL) * NPIX + p] = vj;
                        else
                            outbuf[(size_t)p * 2048 + b * NOC + o * 16 + cL] = vj;
                    }
                } else {
                    f32x4 ap = acc[mt][nt] * vj;
#pragma unroll
                    for (int d = 1; d < 16; d <<= 1) {
                        ap[0] += __shfl_xor(ap[0], d);
                        ap[1] += __shfl_xor(ap[1], d);
                        ap[2] += __shfl_xor(ap[2], d);
                        ap[3] += __shfl_xor(ap[3], d);
                    }
                    if (cL == 0) {
                        float* dst = &aTmp[b * 64 + o * 8 + 4 * h];
                        dst[0] = ap[0]; dst[1] = ap[1]; dst[2] = ap[2]; dst[3] = ap[3];
                    }
                }
            }
        }
        if (it < 2) {
            __syncthreads();   // aTmp writes visible
            if (t < 64) {
                float sum = 0.f;
#pragma unroll
                for (int b = 0; b < BB; ++b) sum += aTmp[b * 64 + t];
                float bij = (it == 0 ? 0.f : bijs[t]) + sum * (1.f / 16.f);
                bijs[t] = bij;
                float mx = bij;
                mx = fmaxf(mx, __shfl_xor(mx, 1));
                mx = fmaxf(mx, __shfl_xor(mx, 2));
                mx = fmaxf(mx, __shfl_xor(mx, 4));
                float e = __expf(bij - mx);
                float se = e;
                se += __shfl_xor(se, 1);
                se += __shfl_xor(se, 2);
                se += __shfl_xor(se, 4);
                cijs[t] = e * __builtin_amdgcn_rcpf(se);
            }
            __syncthreads();
        }
    }
}

// ---------------------------------------------------------------------------
// [pixel][boc] -> [boc][pixel] tiled transpose (fallback path only)
// ---------------------------------------------------------------------------
__global__ void transpose_kernel(const float* __restrict__ vtmp,
                                 float* __restrict__ out)
{
    __shared__ float tile[32][33];
    const int bp = blockIdx.x;
    const int bc = blockIdx.y;
    const int p0 = bp * 32, c0 = bc * 32;
    const int tx = threadIdx.x & 31, ty = threadIdx.x >> 5;

    for (int r = ty; r < 32; r += 8) {
        const int p = p0 + r;
        tile[r][tx] = (p < NPIX) ? vtmp[(size_t)p * 2048 + c0 + tx] : 0.f;
    }
    __syncthreads();
    for (int r = ty; r < 32; r += 8) {
        const int c = c0 + r;
        const int p = p0 + tx;
        if (p < NPIX) out[(size_t)c * NPIX + p] = tile[tx][r];
    }
}

// ---------------------------------------------------------------------------
// Round-1 fp32 fallback (proven correct) — used only if ws too small
// ---------------------------------------------------------------------------
__launch_bounds__(256, 2)
__global__ void capsconv_fp32(const float* __restrict__ x,
                              const float* __restrict__ Wc,
                              const float* __restrict__ bias,
                              float* __restrict__ outbuf,
                              const int direct_out)
{
    __shared__ float As[KC][BI];
    __shared__ float Bsh[KC][NOC];
    __shared__ float cij[64];
    __shared__ float bijs2[64];
    __shared__ float aTmp2[BB * 64];

    const int t  = threadIdx.x;
    const int tn = t & 15;
    const int tm = t >> 4;
    const int p  = blockIdx.x;
    const int px = p / OWH;
    const int py = p % OWH;
    const int row0 = 2 * px - 2;
    const int col0 = 2 * py - 2;
    const bool interior = (px >= 1 && px <= 63 && py >= 1 && py <= 63);

    float C[8][8];
#pragma unroll
    for (int r = 0; r < 8; ++r)
#pragma unroll
        for (int j = 0; j < 8; ++j) C[r][j] = 0.f;

    float areg[8][4];
    float breg[32];

    auto load_chunk = [&](int kc) {
#pragma unroll
        for (int g = 0; g < 8; ++g) {
            const int L    = g * 256 + t;
            const int bi   = L & 127;
            const int cikw = L >> 7;
            const int ci   = kc * 4 + (cikw >> 2);
            const int kw   = cikw & 3;
            const int row  = row0 + kw;
            const float* src = x + (((size_t)(bi * CIN + ci) * WH + row) * WH + col0);
            if (interior) {
                const float2 v01 = *(const float2*)(src);
                const float2 v23 = *(const float2*)(src + 2);
                areg[g][0] = v01.x; areg[g][1] = v01.y;
                areg[g][2] = v23.x; areg[g][3] = v23.y;
            } else {
#pragma unroll
                for (int kh = 0; kh < 4; ++kh) {
                    const int col = col0 + kh;
                    areg[g][kh] = (row >= 0 && row < WH && col >= 0 && col < WH)
                                      ? src[kh] : 0.f;
                }
            }
        }
        {
            const int oc  = t >> 1;
            const int kk0 = (t & 1) * 32;
            const float* wsrc = Wc + (size_t)oc * KTOT + kc * KC + kk0;
#pragma unroll
            for (int m = 0; m < 32; m += 4) {
                const float4 v = *(const float4*)(wsrc + m);
                breg[m] = v.x; breg[m+1] = v.y; breg[m+2] = v.z; breg[m+3] = v.w;
            }
        }
    };

    load_chunk(0);
    for (int kc = 0; kc < NCHUNK; ++kc) {
        __syncthreads();
#pragma unroll
        for (int g = 0; g < 8; ++g) {
            const int L    = g * 256 + t;
            const int bi   = L & 127;
            const int cikw = L >> 7;
            const int kkb  = cikw * 4;
#pragma unroll
            for (int kh = 0; kh < 4; ++kh) As[kkb + kh][bi] = areg[g][kh];
        }
        {
            const int oc  = t >> 1;
            const int kk0 = (t & 1) * 32;
#pragma unroll
            for (int m = 0; m < 32; ++m) Bsh[kk0 + m][oc] = breg[m];
        }
        __syncthreads();
        if (kc < NCHUNK - 1) load_chunk(kc + 1);
#pragma unroll 4
        for (int k = 0; k < KC; ++k) {
            float af[8], bf[8];
            *(float4*)(af)     = *(const float4*)&As[k][tm * 8];
            *(float4*)(af + 4) = *(const float4*)&As[k][tm * 8 + 4];
            *(float4*)(bf)     = *(const float4*)&Bsh[k][tn * 8];
            *(float4*)(bf + 4) = *(const float4*)&Bsh[k][tn * 8 + 4];
#pragma unroll
            for (int r = 0; r < 8; ++r)
#pragma unroll
                for (int j = 0; j < 8; ++j)
                    C[r][j] = fmaf(af[r], bf[j], C[r][j]);
        }
    }
#pragma unroll
    for (int j = 0; j < 8; ++j) {
        const float bj = bias[tn * 8 + j];
#pragma unroll
        for (int r = 0; r < 8; ++r) C[r][j] += bj;
    }

    const int o = tn >> 1;
    __syncthreads();
    if (t < 64) bijs2[t] = 0.f;

    float vout[8];
    for (int it = 0; it < 3; ++it) {
        __syncthreads();
        if (t < 8) {
            const int oo = t;
            float mx = -1e30f;
#pragma unroll
            for (int i = 0; i < 8; ++i) mx = fmaxf(mx, bijs2[i * 8 + oo]);
            float e[8]; float ssum = 0.f;
#pragma unroll
            for (int i = 0; i < 8; ++i) { e[i] = expf(bijs2[i * 8 + oo] - mx); ssum += e[i]; }
            const float inv = 1.f / ssum;
#pragma unroll
            for (int i = 0; i < 8; ++i) cij[i * 8 + oo] = e[i] * inv;
        }
        __syncthreads();
        float cf[8];
#pragma unroll
        for (int i = 0; i < 8; ++i) cf[i] = cij[i * 8 + o];
        float s[8];
#pragma unroll
        for (int j = 0; j < 8; ++j) {
            float acc = 0.f;
#pragma unroll
            for (int r = 0; r < 8; ++r) acc = fmaf(cf[r], C[r][j], acc);
            s[j] = acc;
        }
        float ssq = 0.f;
#pragma unroll
        for (int j = 0; j < 8; ++j) ssq = fmaf(s[j], s[j], ssq);
        ssq += __shfl_xor(ssq, 1);
        const float scale = ssq / ((1.f + ssq) * sqrtf(ssq));
        if (it == 2) {
#pragma unroll
            for (int j = 0; j < 8; ++j) vout[j] = s[j] * scale;
        } else {
            float ap[8];
#pragma unroll
            for (int r = 0; r < 8; ++r) {
                float acc = 0.f;
#pragma unroll
                for (int j = 0; j < 8; ++j) acc = fmaf(C[r][j], s[j] * scale, acc);
                ap[r] = acc;
            }
#pragma unroll
            for (int r = 0; r < 8; ++r) ap[r] += __shfl_xor(ap[r], 1);
            if ((tn & 1) == 0) {
#pragma unroll
                for (int r = 0; r < 8; ++r) aTmp2[tm * 64 + r * 8 + o] = ap[r];
            }
            __syncthreads();
            if (t < 64) {
                float acc = 0.f;
#pragma unroll
                for (int b = 0; b < BB; ++b) acc += aTmp2[b * 64 + t];
                bijs2[t] += acc * (1.f / 16.f);
            }
        }
    }
    if (direct_out) {
#pragma unroll
        for (int j = 0; j < 8; ++j)
            outbuf[(size_t)(tm * NOC + tn * 8 + j) * NPIX + p] = vout[j];
    } else {
        float4* dst = (float4*)(outbuf + (size_t)p * 2048 + tm * NOC + tn * 8);
        dst[0] = make_float4(vout[0], vout[1], vout[2], vout[3]);
        dst[1] = make_float4(vout[4], vout[5], vout[6], vout[7]);
    }
}

extern "C" void kernel_launch(void* const* d_in, const int* in_sizes, int n_in,
                              void* d_out, int out_size, void* d_ws, size_t ws_size,
                              hipStream_t stream)
{
    const float* x    = (const float*)d_in[0];
    const float* Wc   = (const float*)d_in[1];
    const float* bias = (const float*)d_in[2];
    float* out        = (float*)d_out;

    const size_t VT_BYTES = (size_t)NPIX * 2048 * sizeof(float);   // 34,611,200
    const size_t WB_OFF   = VT_BYTES;
    const size_t XB_OFF   = WB_OFF + 65536;
    const size_t TOTAL    = XB_OFF + (size_t)BI * CIN * WH * WH * 2;  // 101,785,600

    if (ws_size >= TOTAL) {
        ushortT* Wbf  = (ushortT*)((char*)d_ws + WB_OFF);
        ushortT* xbfT = (ushortT*)((char*)d_ws + XB_OFF);

        cvtT_kernel<<<S_TOTAL / 64, 256, 0, stream>>>(x, xbfT);
        prep_w_kernel<<<128, 256, 0, stream>>>(Wc, Wbf);
        capsconv_mfma<<<529 * 8, 512, 0, stream>>>(xbfT, Wbf, bias, out, 1);
    } else if (ws_size >= VT_BYTES) {
        float* vtmp = (float*)d_ws;
        capsconv_fp32<<<NPIX, 256, 0, stream>>>(x, Wc, bias, vtmp, 0);
        dim3 g((NPIX + 31) / 32, 2048 / 32);
        transpose_kernel<<<g, 256, 0, stream>>>(vtmp, out);
    } else {
        capsconv_fp32<<<NPIX, 256, 0, stream>>>(x, Wc, bias, out, 1);
    }
}

// Round 5
// 365.748 us; speedup vs baseline: 2.2249x; 1.1250x over previous
//
#include <hip/hip_runtime.h>
#include <math.h>

// Problem constants
#define BB   16      // batch
#define IC   8       // in capsules
#define BI   128     // BB*IC
#define CIN  16      // conv in channels
#define WH   128     // input spatial
#define OWH  65      // output spatial (stride 2, pad 2, k 4)
#define NPIX (OWH*OWH)   // 4225
#define OC   8       // out capsules
#define COUT 16      // out channel per capsule
#define NOC  128     // OC*Cout
#define KTOT 256     // CIN*4*4
#define KC   64      // (fp32 fallback chunk)
#define NCHUNK 4
#define S_TOTAL (CIN*WH*WH)   // 262144 (per-bi s = (ci,row,col) extent)

// MFMA kernel: K chunked by 32 (one mfma-K per chunk), 8 chunks
#define NCHM 8

typedef unsigned short ushortT;
typedef __bf16 bf16x8 __attribute__((ext_vector_type(8)));
typedef float  f32x4  __attribute__((ext_vector_type(4)));

__device__ __forceinline__ ushortT f2bf(float f) {
    unsigned u = __float_as_uint(f);
    unsigned r = (u + 0x7fffu + ((u >> 16) & 1u)) >> 16;
    return (ushortT)r;
}

// Raw barrier: orders LDS (lgkmcnt(0)) but does NOT drain vmcnt -> global
// prefetches ride across (T4). sched_barrier pins loads below (rule #18).
#define GEMM_BARRIER() do {                                   \
    asm volatile("s_waitcnt lgkmcnt(0)" ::: "memory");        \
    __builtin_amdgcn_s_barrier();                             \
    __builtin_amdgcn_sched_barrier(0);                        \
} while (0)

// ---------------------------------------------------------------------------
// Pre-pass 1: x fp32 [bi][ci][row][col] -> bf16 TRANSPOSED xbfT[s][bi],
// s = (ci*WH+row)*WH+col (bi innermost => GEMM A-staging is coalesced).
// LDS-tiled: block = 64 consecutive s x all 128 bi.
// ---------------------------------------------------------------------------
__global__ void cvtT_kernel(const float* __restrict__ x,
                            ushortT* __restrict__ xbfT)
{
    __shared__ ushortT tile[64 * 136];   // [sIdx][bi], stride 136, XOR-swizzled
    const int t  = threadIdx.x;          // 0..255
    const int s0 = blockIdx.x * 64;      // 4096 blocks

    // load: 2048 float4 (128 bi x 16 s-quads); 8 per thread
#pragma unroll
    for (int k = 0; k < 8; ++k) {
        const int j  = t + k * 256;
        const int bi = j >> 4, s4 = j & 15;
        const float4 v = *(const float4*)(x + (size_t)bi * S_TOTAL + s0 + s4 * 4);
        const int si = s4 * 4;
        tile[(si    ) * 136 + (bi ^ (((si    ) & 15) << 3))] = f2bf(v.x);
        tile[(si + 1) * 136 + (bi ^ (((si + 1) & 15) << 3))] = f2bf(v.y);
        tile[(si + 2) * 136 + (bi ^ (((si + 2) & 15) << 3))] = f2bf(v.z);
        tile[(si + 3) * 136 + (bi ^ (((si + 3) & 15) << 3))] = f2bf(v.w);
    }
    __syncthreads();
    // store: 1024 x 16B (64 s x 16 bi-octets); 4 per thread, fully coalesced
#pragma unroll
    for (int k = 0; k < 4; ++k) {
        const int j  = t + k * 256;
        const int sI = j >> 4, g = j & 15;
        const uint4 val = *(const uint4*)&tile[sI * 136 + ((g ^ (sI & 15)) << 3)];
        *(uint4*)(xbfT + (size_t)(s0 + sI) * 128 + g * 8) = val;
    }
}

// ---------------------------------------------------------------------------
// Pre-pass 2: W fp32 [oc][k] -> bf16 prepacked fragment image:
//   Wbf[(kpg*128+oc)*8 + j]   (k = kpg*8 + j, kpg = 0..31)
// ---------------------------------------------------------------------------
__global__ void prep_w_kernel(const float* __restrict__ W,
                              ushortT* __restrict__ Wbf)
{
    int idx = blockIdx.x * 256 + threadIdx.x;   // 32768 total
    int oc = idx >> 8, k = idx & 255;
    int kpg = k >> 3, j = k & 7;
    Wbf[((size_t)kpg * 128 + oc) * 8 + j] = f2bf(W[idx]);
}

// ---------------------------------------------------------------------------
// Fused MFMA kernel, 512 threads (8 waves). Wave w owns a 64x32 C quadrant:
// rows [64*(w>>2), +64) x cols [32*(w&3), +32) as 4x2 tiles of 16x16.
//
// v6 (from v5, which passed on HW):
//  - GEMM_BARRIER replaces __syncthreads in the K-loop: no vmcnt(0) drain,
//    so the ring-3 A-prefetch (issued 2-3 chunks ahead) and the hoisted
//    global B loads actually stay in flight across barriers (T4).
//  - Routing agreement reduce uses the fold trick: rows folded into lanes
//    via cndmask+shfl (5 shuffles vs 16); lanes cL<4 write aTmp in parallel.
//  Data image identical to v4/v5 (proven): A swizzle byte^=((byte>>7)&7)<<4.
// C/D: col=lane&15 -> oc-col c, row=4*quad+reg -> (b,i). direct_out write.
// ---------------------------------------------------------------------------
__launch_bounds__(512, 4)
__global__ void capsconv_mfma(const ushortT* __restrict__ xbfT,
                              const ushortT* __restrict__ Wbf,
                              const float* __restrict__ bias,
                              float* __restrict__ outbuf,
                              const int direct_out)
{
    __shared__ __align__(16) ushortT As[3][4 * 128 * 8];   // 3 x 8 KB ring
    __shared__ float cijs[64];       // [o][i]
    __shared__ float bijs[64];       // [o][i] (wave 0 only)
    __shared__ float aTmp[16 * 64];  // [b][o*8+i]

    const int t  = threadIdx.x;      // 0..511
    const int g8 = blockIdx.x;
    int p = (g8 & 7) * 529 + (g8 >> 3);     // XCD-contiguous pixel strips
    if (p >= NPIX) return;

    const int w  = t >> 6;       // wave id 0..7
    const int ln = t & 63;
    const int q  = ln >> 4;      // quad
    const int cL = ln & 15;      // lane col (c within tile)
    const int h  = q & 1;        // i-half
    const int mrow_base = 64 * (w >> 2);   // 0 or 64
    const int ncol_base = 32 * (w & 3);    // 0,32,64,96

    const int px = p / OWH;
    const int py = p % OWH;
    const int row0 = 2 * px - 2;
    const int col0 = 2 * py - 2;

    f32x4 acc[4][2];
#pragma unroll
    for (int mt = 0; mt < 4; ++mt)
#pragma unroll
        for (int nt = 0; nt < 2; ++nt) acc[mt][nt] = (f32x4){0.f, 0.f, 0.f, 0.f};

    // ---- A staging map (per thread, chunk-invariant except source ci) ----
    const int g     = t & 15;        // bi octet
    const int sI    = t >> 4;        // 0..31
    const int colw  = sI & 3;
    const int rowl  = (sI >> 2) & 3;
    const int cih   = sI >> 4;       // 0..1
    const int srow  = row0 + rowl;
    const int scol  = col0 + colw;
    const bool ok   = (srow >= 0 && srow < WH && scol >= 0 && scol < WH);
    const size_t aoff0 = ok
        ? ((size_t)((cih * WH + srow) * WH + scol) * 128 + g * 8)
        : 0;
    // LDS dest (bytes within As[buf]); bits 4-6 of wbase are zero.
    const int kpg   = cih * 2 + (rowl >> 1);
    const int jj    = (rowl & 1) * 4 + colw;
    const int wbase = (kpg * 128 + g * 8) * 16 + jj * 2;
    const int gk7   = g & 7;

    // fragment read byte offsets (swizzled), chunk-invariant
    int aRd[4];
#pragma unroll
    for (int mt = 0; mt < 4; ++mt) {
        const int by = (q * 128 + mrow_base + mt * 16 + cL) * 16;
        aRd[mt] = by ^ (((by >> 7) & 7) << 4);
    }

    uint4 aR[2];   // pending A loads (2 in flight)

    auto loadA = [&](uint4& r, int kc) {
        r = make_uint4(0u, 0u, 0u, 0u);
        if (ok) r = *(const uint4*)(xbfT + aoff0 + (size_t)kc * (2 * WH * WH * 128));
    };
    auto storeA = [&](int buf, const uint4& r) {
        char* ab = (char*)&As[buf][0];
        const ushortT* av = (const ushortT*)&r;
#pragma unroll
        for (int c = 0; c < 8; ++c)
            *(ushortT*)(ab + wbase + ((c ^ gk7) << 4)) = av[c];
    };

    // prologue: chunks 0,1 in flight; store 0; load 2 into freed slot
    loadA(aR[0], 0);
    loadA(aR[1], 1);
    storeA(0, aR[0]);          // counted vmcnt wait for chunk-0 load lands here
    loadA(aR[0], 2);
    GEMM_BARRIER();            // buf0 visible; chunks 1,2 still in flight

#pragma unroll
    for (int kc = 0; kc < NCHM; ++kc) {
        const int buf = kc % 3;
        {
            const char* abase = (const char*)&As[buf][0];
            bf16x8 af[4], bfr[2];
#pragma unroll
            for (int mt = 0; mt < 4; ++mt)
                af[mt] = *(const bf16x8*)(abase + aRd[mt]);
            // B direct from global (L2-hot, no barrier dependency)
            const ushortT* bsrc = Wbf + kc * 4096 + (q * 128 + ncol_base + cL) * 8;
            bfr[0] = *(const bf16x8*)(bsrc);
            bfr[1] = *(const bf16x8*)(bsrc + 128);
#pragma unroll
            for (int mt = 0; mt < 4; ++mt)
#pragma unroll
                for (int nt = 0; nt < 2; ++nt)
                    acc[mt][nt] = __builtin_amdgcn_mfma_f32_16x16x32_bf16(
                        af[mt], bfr[nt], acc[mt][nt], 0, 0, 0);
        }
        // ring maintenance: store chunk kc+1 (loaded 2 iters ago), issue kc+3
        if (kc + 1 < NCHM) storeA((kc + 1) % 3, aR[(kc + 1) & 1]);
        if (kc + 3 < NCHM) loadA(aR[(kc + 3) & 1], kc + 3);
        GEMM_BARRIER();
    }

    // bias epilogue
#pragma unroll
    for (int nt = 0; nt < 2; ++nt) {
        const float bv = bias[ncol_base + nt * 16 + cL];
#pragma unroll
        for (int mt = 0; mt < 4; ++mt) acc[mt][nt] += bv;
    }

    // ---------------- dynamic routing (3 iters) ----------------
    // iter 0: b_ij = 0 -> c_ij = 1/8 exactly (no softmax needed).
    for (int it = 0; it < 3; ++it) {
        float4 cf4[2];
        if (it == 0) {
#pragma unroll
            for (int nt = 0; nt < 2; ++nt)
                cf4[nt] = make_float4(0.125f, 0.125f, 0.125f, 0.125f);
        } else {
#pragma unroll
            for (int nt = 0; nt < 2; ++nt)
                cf4[nt] = *(const float4*)&cijs[(2 * (w & 3) + nt) * 8 + 4 * h];
        }

#pragma unroll
        for (int mt = 0; mt < 4; ++mt) {
            const int b = 8 * (w >> 2) + 2 * mt + (q >> 1);
#pragma unroll
            for (int nt = 0; nt < 2; ++nt) {
                const int o = 2 * (w & 3) + nt;
                const float4 cf = cf4[nt];
                float sp = cf.x * acc[mt][nt][0] + cf.y * acc[mt][nt][1]
                         + cf.z * acc[mt][nt][2] + cf.w * acc[mt][nt][3];
                float s = sp + __shfl_xor(sp, 16);
                float ssq = s * s;
#pragma unroll
                for (int d = 1; d < 16; d <<= 1) ssq += __shfl_xor(ssq, d);
                const float scale = sqrtf(ssq) * __builtin_amdgcn_rcpf(1.f + ssq);
                const float vj = s * scale;

                if (it == 2) {
                    if (q == 0 || q == 2) {
                        if (direct_out)
                            outbuf[(size_t)(b * NOC + o * 16 + cL) * NPIX + p] = vj;
                        else
                            outbuf[(size_t)p * 2048 + b * NOC + o * 16 + cL] = vj;
                    }
                } else {
                    // fold trick: rows -> lanes; lane cL ends with
                    // row (cL&3) summed over the 16 cL lanes (5 shuffles).
                    f32x4 ap = acc[mt][nt] * vj;
                    const bool k1 = (cL & 1) != 0;
                    float e0 = k1 ? ap[1] : ap[0];
                    float o0 = k1 ? ap[0] : ap[1];
                    float e1 = k1 ? ap[3] : ap[2];
                    float o1 = k1 ? ap[2] : ap[3];
                    e0 += __shfl_xor(o0, 1);
                    e1 += __shfl_xor(o1, 1);
                    const bool k2 = (cL & 2) != 0;
                    float f0 = k2 ? e1 : e0;
                    float f1 = k2 ? e0 : e1;
                    f0 += __shfl_xor(f1, 2);
                    f0 += __shfl_xor(f0, 4);
                    f0 += __shfl_xor(f0, 8);
                    if (cL < 4)
                        aTmp[b * 64 + o * 8 + 4 * h + cL] = f0;
                }
            }
        }
        if (it < 2) {
            __syncthreads();   // aTmp writes visible
            if (t < 64) {
                float sum = 0.f;
#pragma unroll
                for (int b = 0; b < BB; ++b) sum += aTmp[b * 64 + t];
                float bij = (it == 0 ? 0.f : bijs[t]) + sum * (1.f / 16.f);
                bijs[t] = bij;
                float mx = bij;
                mx = fmaxf(mx, __shfl_xor(mx, 1));
                mx = fmaxf(mx, __shfl_xor(mx, 2));
                mx = fmaxf(mx, __shfl_xor(mx, 4));
                float e = __expf(bij - mx);
                float se = e;
                se += __shfl_xor(se, 1);
                se += __shfl_xor(se, 2);
                se += __shfl_xor(se, 4);
                cijs[t] = e * __builtin_amdgcn_rcpf(se);
            }
            __syncthreads();
        }
    }
}

// ---------------------------------------------------------------------------
// [pixel][boc] -> [boc][pixel] tiled transpose (fallback path only)
// ---------------------------------------------------------------------------
__global__ void transpose_kernel(const float* __restrict__ vtmp,
                                 float* __restrict__ out)
{
    __shared__ float tile[32][33];
    const int bp = blockIdx.x;
    const int bc = blockIdx.y;
    const int p0 = bp * 32, c0 = bc * 32;
    const int tx = threadIdx.x & 31, ty = threadIdx.x >> 5;

    for (int r = ty; r < 32; r += 8) {
        const int p = p0 + r;
        tile[r][tx] = (p < NPIX) ? vtmp[(size_t)p * 2048 + c0 + tx] : 0.f;
    }
    __syncthreads();
    for (int r = ty; r < 32; r += 8) {
        const int c = c0 + r;
        const int p = p0 + tx;
        if (p < NPIX) out[(size_t)c * NPIX + p] = tile[tx][r];
    }
}

// ---------------------------------------------------------------------------
// Round-1 fp32 fallback (proven correct) — used only if ws too small
// ---------------------------------------------------------------------------
__launch_bounds__(256, 2)
__global__ void capsconv_fp32(const float* __restrict__ x,
                              const float* __restrict__ Wc,
                              const float* __restrict__ bias,
                              float* __restrict__ outbuf,
                              const int direct_out)
{
    __shared__ float As[KC][BI];
    __shared__ float Bsh[KC][NOC];
    __shared__ float cij[64];
    __shared__ float bijs2[64];
    __shared__ float aTmp2[BB * 64];

    const int t  = threadIdx.x;
    const int tn = t & 15;
    const int tm = t >> 4;
    const int p  = blockIdx.x;
    const int px = p / OWH;
    const int py = p % OWH;
    const int row0 = 2 * px - 2;
    const int col0 = 2 * py - 2;
    const bool interior = (px >= 1 && px <= 63 && py >= 1 && py <= 63);

    float C[8][8];
#pragma unroll
    for (int r = 0; r < 8; ++r)
#pragma unroll
        for (int j = 0; j < 8; ++j) C[r][j] = 0.f;

    float areg[8][4];
    float breg[32];

    auto load_chunk = [&](int kc) {
#pragma unroll
        for (int g = 0; g < 8; ++g) {
            const int L    = g * 256 + t;
            const int bi   = L & 127;
            const int cikw = L >> 7;
            const int ci   = kc * 4 + (cikw >> 2);
            const int kw   = cikw & 3;
            const int row  = row0 + kw;
            const float* src = x + (((size_t)(bi * CIN + ci) * WH + row) * WH + col0);
            if (interior) {
                const float2 v01 = *(const float2*)(src);
                const float2 v23 = *(const float2*)(src + 2);
                areg[g][0] = v01.x; areg[g][1] = v01.y;
                areg[g][2] = v23.x; areg[g][3] = v23.y;
            } else {
#pragma unroll
                for (int kh = 0; kh < 4; ++kh) {
                    const int col = col0 + kh;
                    areg[g][kh] = (row >= 0 && row < WH && col >= 0 && col < WH)
                                      ? src[kh] : 0.f;
                }
            }
        }
        {
            const int oc  = t >> 1;
            const int kk0 = (t & 1) * 32;
            const float* wsrc = Wc + (size_t)oc * KTOT + kc * KC + kk0;
#pragma unroll
            for (int m = 0; m < 32; m += 4) {
                const float4 v = *(const float4*)(wsrc + m);
                breg[m] = v.x; breg[m+1] = v.y; breg[m+2] = v.z; breg[m+3] = v.w;
            }
        }
    };

    load_chunk(0);
    for (int kc = 0; kc < NCHUNK; ++kc) {
        __syncthreads();
#pragma unroll
        for (int g = 0; g < 8; ++g) {
            const int L    = g * 256 + t;
            const int bi   = L & 127;
            const int cikw = L >> 7;
            const int kkb  = cikw * 4;
#pragma unroll
            for (int kh = 0; kh < 4; ++kh) As[kkb + kh][bi] = areg[g][kh];
        }
        {
            const int oc  = t >> 1;
            const int kk0 = (t & 1) * 32;
#pragma unroll
            for (int m = 0; m < 32; ++m) Bsh[kk0 + m][oc] = breg[m];
        }
        __syncthreads();
        if (kc < NCHUNK - 1) load_chunk(kc + 1);
#pragma unroll 4
        for (int k = 0; k < KC; ++k) {
            float af[8], bf[8];
            *(float4*)(af)     = *(const float4*)&As[k][tm * 8];
            *(float4*)(af + 4) = *(const float4*)&As[k][tm * 8 + 4];
            *(float4*)(bf)     = *(const float4*)&Bsh[k][tn * 8];
            *(float4*)(bf + 4) = *(const float4*)&Bsh[k][tn * 8 + 4];
#pragma unroll
            for (int r = 0; r < 8; ++r)
#pragma unroll
                for (int j = 0; j < 8; ++j)
                    C[r][j] = fmaf(af[r], bf[j], C[r][j]);
        }
    }
#pragma unroll
    for (int j = 0; j < 8; ++j) {
        const float bj = bias[tn * 8 + j];
#pragma unroll
        for (int r = 0; r < 8; ++r) C[r][j] += bj;
    }

    const int o = tn >> 1;
    __syncthreads();
    if (t < 64) bijs2[t] = 0.f;

    float vout[8];
    for (int it = 0; it < 3; ++it) {
        __syncthreads();
        if (t < 8) {
            const int oo = t;
            float mx = -1e30f;
#pragma unroll
            for (int i = 0; i < 8; ++i) mx = fmaxf(mx, bijs2[i * 8 + oo]);
            float e[8]; float ssum = 0.f;
#pragma unroll
            for (int i = 0; i < 8; ++i) { e[i] = expf(bijs2[i * 8 + oo] - mx); ssum += e[i]; }
            const float inv = 1.f / ssum;
#pragma unroll
            for (int i = 0; i < 8; ++i) cij[i * 8 + oo] = e[i] * inv;
        }
        __syncthreads();
        float cf[8];
#pragma unroll
        for (int i = 0; i < 8; ++i) cf[i] = cij[i * 8 + o];
        float s[8];
#pragma unroll
        for (int j = 0; j < 8; ++j) {
            float acc = 0.f;
#pragma unroll
            for (int r = 0; r < 8; ++r) acc = fmaf(cf[r], C[r][j], acc);
            s[j] = acc;
        }
        float ssq = 0.f;
#pragma unroll
        for (int j = 0; j < 8; ++j) ssq = fmaf(s[j], s[j], ssq);
        ssq += __shfl_xor(ssq, 1);
        const float scale = ssq / ((1.f + ssq) * sqrtf(ssq));
        if (it == 2) {
#pragma unroll
            for (int j = 0; j < 8; ++j) vout[j] = s[j] * scale;
        } else {
            float ap[8];
#pragma unroll
            for (int r = 0; r < 8; ++r) {
                float acc = 0.f;
#pragma unroll
                for (int j = 0; j < 8; ++j) acc = fmaf(C[r][j], s[j] * scale, acc);
                ap[r] = acc;
            }
#pragma unroll
            for (int r = 0; r < 8; ++r) ap[r] += __shfl_xor(ap[r], 1);
            if ((tn & 1) == 0) {
#pragma unroll
                for (int r = 0; r < 8; ++r) aTmp2[tm * 64 + r * 8 + o] = ap[r];
            }
            __syncthreads();
            if (t < 64) {
                float acc = 0.f;
#pragma unroll
                for (int b = 0; b < BB; ++b) acc += aTmp2[b * 64 + t];
                bijs2[t] += acc * (1.f / 16.f);
            }
        }
    }
    if (direct_out) {
#pragma unroll
        for (int j = 0; j < 8; ++j)
            outbuf[(size_t)(tm * NOC + tn * 8 + j) * NPIX + p] = vout[j];
    } else {
        float4* dst = (float4*)(outbuf + (size_t)p * 2048 + tm * NOC + tn * 8);
        dst[0] = make_float4(vout[0], vout[1], vout[2], vout[3]);
        dst[1] = make_float4(vout[4], vout[5], vout[6], vout[7]);
    }
}

extern "C" void kernel_launch(void* const* d_in, const int* in_sizes, int n_in,
                              void* d_out, int out_size, void* d_ws, size_t ws_size,
                              hipStream_t stream)
{
    const float* x    = (const float*)d_in[0];
    const float* Wc   = (const float*)d_in[1];
    const float* bias = (const float*)d_in[2];
    float* out        = (float*)d_out;

    const size_t VT_BYTES = (size_t)NPIX * 2048 * sizeof(float);   // 34,611,200
    const size_t WB_OFF   = VT_BYTES;
    const size_t XB_OFF   = WB_OFF + 65536;
    const size_t TOTAL    = XB_OFF + (size_t)BI * CIN * WH * WH * 2;  // 101,785,600

    if (ws_size >= TOTAL) {
        ushortT* Wbf  = (ushortT*)((char*)d_ws + WB_OFF);
        ushortT* xbfT = (ushortT*)((char*)d_ws + XB_OFF);

        cvtT_kernel<<<S_TOTAL / 64, 256, 0, stream>>>(x, xbfT);
        prep_w_kernel<<<128, 256, 0, stream>>>(Wc, Wbf);
        capsconv_mfma<<<529 * 8, 512, 0, stream>>>(xbfT, Wbf, bias, out, 1);
    } else if (ws_size >= VT_BYTES) {
        float* vtmp = (float*)d_ws;
        capsconv_fp32<<<NPIX, 256, 0, stream>>>(x, Wc, bias, vtmp, 0);
        dim3 g((NPIX + 31) / 32, 2048 / 32);
        transpose_kernel<<<g, 256, 0, stream>>>(vtmp, out);
    } else {
        capsconv_fp32<<<NPIX, 256, 0, stream>>>(x, Wc, bias, out, 1);
    }
}

// Round 6
// 336.589 us; speedup vs baseline: 2.4176x; 1.0866x over previous
//
#include <hip/hip_runtime.h>
#include <math.h>

// Problem constants
#define BB   16      // batch
#define IC   8       // in capsules
#define BI   128     // BB*IC
#define CIN  16      // conv in channels
#define WH   128     // input spatial
#define OWH  65      // output spatial (stride 2, pad 2, k 4)
#define NPIX (OWH*OWH)   // 4225
#define OC   8       // out capsules
#define COUT 16      // out channel per capsule
#define NOC  128     // OC*Cout
#define KTOT 256     // CIN*4*4
#define KC   64      // (fp32 fallback chunk)
#define NCHUNK 4
#define S_TOTAL (CIN*WH*WH)   // 262144 (per-bi s = (ci,row,col) extent)

// MFMA kernel: K chunked by 32 (one mfma-K per chunk), 8 chunks
#define NCHM 8

typedef unsigned short ushortT;
typedef __bf16 bf16x8 __attribute__((ext_vector_type(8)));
typedef float  f32x4  __attribute__((ext_vector_type(4)));

__device__ __forceinline__ ushortT f2bf(float f) {
    unsigned u = __float_as_uint(f);
    unsigned r = (u + 0x7fffu + ((u >> 16) & 1u)) >> 16;
    return (ushortT)r;
}

// DPP lane move within 16-lane rows (rows == our quads): VALU pipe, no LDS.
// 0xB1 = quad_perm[1,0,3,2] (xor1), 0x4E = quad_perm[2,3,0,1] (xor2),
// 0x124 = row_ror:4, 0x128 = row_ror:8 (rotation all-reduce over {+0,+4,+8,+12}).
template <int CTRL>
__device__ __forceinline__ float dppMov(float x) {
    return __int_as_float(__builtin_amdgcn_update_dpp(
        0, __float_as_int(x), CTRL, 0xF, 0xF, true));
}

// Raw barrier: orders LDS (lgkmcnt(0)) but does NOT drain vmcnt -> global
// prefetches ride across (T4). sched_barrier pins loads below (rule #18).
#define GEMM_BARRIER() do {                                   \
    asm volatile("s_waitcnt lgkmcnt(0)" ::: "memory");        \
    __builtin_amdgcn_s_barrier();                             \
    __builtin_amdgcn_sched_barrier(0);                        \
} while (0)

// ---------------------------------------------------------------------------
// Pre-pass 1: x fp32 [bi][ci][row][col] -> bf16 TRANSPOSED xbfT[s][bi],
// s = (ci*WH+row)*WH+col (bi innermost => GEMM A-staging is coalesced).
// LDS-tiled: block = 64 consecutive s x all 128 bi.
// ---------------------------------------------------------------------------
__global__ void cvtT_kernel(const float* __restrict__ x,
                            ushortT* __restrict__ xbfT)
{
    __shared__ ushortT tile[64 * 136];   // [sIdx][bi], stride 136, XOR-swizzled
    const int t  = threadIdx.x;          // 0..255
    const int s0 = blockIdx.x * 64;      // 4096 blocks

    // load: 2048 float4 (128 bi x 16 s-quads); 8 per thread
#pragma unroll
    for (int k = 0; k < 8; ++k) {
        const int j  = t + k * 256;
        const int bi = j >> 4, s4 = j & 15;
        const float4 v = *(const float4*)(x + (size_t)bi * S_TOTAL + s0 + s4 * 4);
        const int si = s4 * 4;
        tile[(si    ) * 136 + (bi ^ (((si    ) & 15) << 3))] = f2bf(v.x);
        tile[(si + 1) * 136 + (bi ^ (((si + 1) & 15) << 3))] = f2bf(v.y);
        tile[(si + 2) * 136 + (bi ^ (((si + 2) & 15) << 3))] = f2bf(v.z);
        tile[(si + 3) * 136 + (bi ^ (((si + 3) & 15) << 3))] = f2bf(v.w);
    }
    __syncthreads();
    // store: 1024 x 16B (64 s x 16 bi-octets); 4 per thread, fully coalesced
#pragma unroll
    for (int k = 0; k < 4; ++k) {
        const int j  = t + k * 256;
        const int sI = j >> 4, g = j & 15;
        const uint4 val = *(const uint4*)&tile[sI * 136 + ((g ^ (sI & 15)) << 3)];
        *(uint4*)(xbfT + (size_t)(s0 + sI) * 128 + g * 8) = val;
    }
}

// ---------------------------------------------------------------------------
// Pre-pass 2: W fp32 [oc][k] -> bf16 prepacked fragment image:
//   Wbf[(kpg*128+oc)*8 + j]   (k = kpg*8 + j, kpg = 0..31)
// ---------------------------------------------------------------------------
__global__ void prep_w_kernel(const float* __restrict__ W,
                              ushortT* __restrict__ Wbf)
{
    int idx = blockIdx.x * 256 + threadIdx.x;   // 32768 total
    int oc = idx >> 8, k = idx & 255;
    int kpg = k >> 3, j = k & 7;
    Wbf[((size_t)kpg * 128 + oc) * 8 + j] = f2bf(W[idx]);
}

// ---------------------------------------------------------------------------
// Fused MFMA kernel, 512 threads (8 waves). Wave w owns a 64x32 C quadrant:
// rows [64*(w>>2), +64) x cols [32*(w&3), +32) as 4x2 tiles of 16x16.
//
// v7 (from v6, which passed on HW): routing reductions moved off the LDS
// pipe onto DPP (VALU): xor1/xor2 -> quad_perm, xor4;xor8 butterfly ->
// row_ror:4 + row_ror:8 rotation all-reduce (same orbit sum, different
// addition order). DPP rows (16 lanes) == quads, so row ops never cross a
// quad boundary. shfl16 (h-combine) and the wave-0 softmax keep shfl.
// GEMM/staging/layouts identical to v6.
// C/D: col=lane&15 -> oc-col c, row=4*quad+reg -> (b,i). direct_out write.
// ---------------------------------------------------------------------------
__launch_bounds__(512, 4)
__global__ void capsconv_mfma(const ushortT* __restrict__ xbfT,
                              const ushortT* __restrict__ Wbf,
                              const float* __restrict__ bias,
                              float* __restrict__ outbuf,
                              const int direct_out)
{
    __shared__ __align__(16) ushortT As[3][4 * 128 * 8];   // 3 x 8 KB ring
    __shared__ float cijs[64];       // [o][i]
    __shared__ float bijs[64];       // [o][i] (wave 0 only)
    __shared__ float aTmp[16 * 64];  // [b][o*8+i]

    const int t  = threadIdx.x;      // 0..511
    const int g8 = blockIdx.x;
    int p = (g8 & 7) * 529 + (g8 >> 3);     // XCD-contiguous pixel strips
    if (p >= NPIX) return;

    const int w  = t >> 6;       // wave id 0..7
    const int ln = t & 63;
    const int q  = ln >> 4;      // quad
    const int cL = ln & 15;      // lane col (c within tile)
    const int h  = q & 1;        // i-half
    const int mrow_base = 64 * (w >> 2);   // 0 or 64
    const int ncol_base = 32 * (w & 3);    // 0,32,64,96

    const int px = p / OWH;
    const int py = p % OWH;
    const int row0 = 2 * px - 2;
    const int col0 = 2 * py - 2;

    f32x4 acc[4][2];
#pragma unroll
    for (int mt = 0; mt < 4; ++mt)
#pragma unroll
        for (int nt = 0; nt < 2; ++nt) acc[mt][nt] = (f32x4){0.f, 0.f, 0.f, 0.f};

    // ---- A staging map (per thread, chunk-invariant except source ci) ----
    const int g     = t & 15;        // bi octet
    const int sI    = t >> 4;        // 0..31
    const int colw  = sI & 3;
    const int rowl  = (sI >> 2) & 3;
    const int cih   = sI >> 4;       // 0..1
    const int srow  = row0 + rowl;
    const int scol  = col0 + colw;
    const bool ok   = (srow >= 0 && srow < WH && scol >= 0 && scol < WH);
    const size_t aoff0 = ok
        ? ((size_t)((cih * WH + srow) * WH + scol) * 128 + g * 8)
        : 0;
    // LDS dest (bytes within As[buf]); bits 4-6 of wbase are zero.
    const int kpg   = cih * 2 + (rowl >> 1);
    const int jj    = (rowl & 1) * 4 + colw;
    const int wbase = (kpg * 128 + g * 8) * 16 + jj * 2;
    const int gk7   = g & 7;

    // fragment read byte offsets (swizzled), chunk-invariant
    int aRd[4];
#pragma unroll
    for (int mt = 0; mt < 4; ++mt) {
        const int by = (q * 128 + mrow_base + mt * 16 + cL) * 16;
        aRd[mt] = by ^ (((by >> 7) & 7) << 4);
    }

    uint4 aR[2];   // pending A loads (2 in flight)

    auto loadA = [&](uint4& r, int kc) {
        r = make_uint4(0u, 0u, 0u, 0u);
        if (ok) r = *(const uint4*)(xbfT + aoff0 + (size_t)kc * (2 * WH * WH * 128));
    };
    auto storeA = [&](int buf, const uint4& r) {
        char* ab = (char*)&As[buf][0];
        const ushortT* av = (const ushortT*)&r;
#pragma unroll
        for (int c = 0; c < 8; ++c)
            *(ushortT*)(ab + wbase + ((c ^ gk7) << 4)) = av[c];
    };

    // prologue: chunks 0,1 in flight; store 0; load 2 into freed slot
    loadA(aR[0], 0);
    loadA(aR[1], 1);
    storeA(0, aR[0]);          // counted vmcnt wait for chunk-0 load lands here
    loadA(aR[0], 2);
    GEMM_BARRIER();            // buf0 visible; chunks 1,2 still in flight

#pragma unroll
    for (int kc = 0; kc < NCHM; ++kc) {
        const int buf = kc % 3;
        {
            const char* abase = (const char*)&As[buf][0];
            bf16x8 af[4], bfr[2];
#pragma unroll
            for (int mt = 0; mt < 4; ++mt)
                af[mt] = *(const bf16x8*)(abase + aRd[mt]);
            // B direct from global (L2-hot, no barrier dependency)
            const ushortT* bsrc = Wbf + kc * 4096 + (q * 128 + ncol_base + cL) * 8;
            bfr[0] = *(const bf16x8*)(bsrc);
            bfr[1] = *(const bf16x8*)(bsrc + 128);
#pragma unroll
            for (int mt = 0; mt < 4; ++mt)
#pragma unroll
                for (int nt = 0; nt < 2; ++nt)
                    acc[mt][nt] = __builtin_amdgcn_mfma_f32_16x16x32_bf16(
                        af[mt], bfr[nt], acc[mt][nt], 0, 0, 0);
        }
        // ring maintenance: store chunk kc+1 (loaded 2 iters ago), issue kc+3
        if (kc + 1 < NCHM) storeA((kc + 1) % 3, aR[(kc + 1) & 1]);
        if (kc + 3 < NCHM) loadA(aR[(kc + 3) & 1], kc + 3);
        GEMM_BARRIER();
    }

    // bias epilogue
#pragma unroll
    for (int nt = 0; nt < 2; ++nt) {
        const float bv = bias[ncol_base + nt * 16 + cL];
#pragma unroll
        for (int mt = 0; mt < 4; ++mt) acc[mt][nt] += bv;
    }

    // ---------------- dynamic routing (3 iters) ----------------
    // iter 0: b_ij = 0 -> c_ij = 1/8 exactly (no softmax needed).
    for (int it = 0; it < 3; ++it) {
        float4 cf4[2];
        if (it == 0) {
#pragma unroll
            for (int nt = 0; nt < 2; ++nt)
                cf4[nt] = make_float4(0.125f, 0.125f, 0.125f, 0.125f);
        } else {
#pragma unroll
            for (int nt = 0; nt < 2; ++nt)
                cf4[nt] = *(const float4*)&cijs[(2 * (w & 3) + nt) * 8 + 4 * h];
        }

#pragma unroll
        for (int mt = 0; mt < 4; ++mt) {
            const int b = 8 * (w >> 2) + 2 * mt + (q >> 1);
#pragma unroll
            for (int nt = 0; nt < 2; ++nt) {
                const int o = 2 * (w & 3) + nt;
                const float4 cf = cf4[nt];
                float sp = cf.x * acc[mt][nt][0] + cf.y * acc[mt][nt][1]
                         + cf.z * acc[mt][nt][2] + cf.w * acc[mt][nt][3];
                float s = sp + __shfl_xor(sp, 16);
                // ssq = sum over the 16 cL lanes of s^2 (DPP, VALU-only):
                // xor1, xor2 butterflies then ror4+ror8 rotation completion.
                float ssq = s * s;
                ssq += dppMov<0xB1>(ssq);
                ssq += dppMov<0x4E>(ssq);
                ssq += dppMov<0x124>(ssq);
                ssq += dppMov<0x128>(ssq);
                const float scale = sqrtf(ssq) * __builtin_amdgcn_rcpf(1.f + ssq);
                const float vj = s * scale;

                if (it == 2) {
                    if (q == 0 || q == 2) {
                        if (direct_out)
                            outbuf[(size_t)(b * NOC + o * 16 + cL) * NPIX + p] = vj;
                        else
                            outbuf[(size_t)p * 2048 + b * NOC + o * 16 + cL] = vj;
                    }
                } else {
                    // fold trick: rows -> lanes (DPP impl, same lane algebra):
                    // lane cL ends with row (cL&3) summed over the 16 cL lanes.
                    f32x4 ap = acc[mt][nt] * vj;
                    const bool k1 = (cL & 1) != 0;
                    float e0 = k1 ? ap[1] : ap[0];
                    float o0 = k1 ? ap[0] : ap[1];
                    float e1 = k1 ? ap[3] : ap[2];
                    float o1 = k1 ? ap[2] : ap[3];
                    e0 += dppMov<0xB1>(o0);
                    e1 += dppMov<0xB1>(o1);
                    const bool k2 = (cL & 2) != 0;
                    float f0 = k2 ? e1 : e0;
                    float f1 = k2 ? e0 : e1;
                    f0 += dppMov<0x4E>(f1);
                    f0 += dppMov<0x124>(f0);
                    f0 += dppMov<0x128>(f0);
                    if (cL < 4)
                        aTmp[b * 64 + o * 8 + 4 * h + cL] = f0;
                }
            }
        }
        if (it < 2) {
            __syncthreads();   // aTmp writes visible
            if (t < 64) {
                float sum = 0.f;
#pragma unroll
                for (int b = 0; b < BB; ++b) sum += aTmp[b * 64 + t];
                float bij = (it == 0 ? 0.f : bijs[t]) + sum * (1.f / 16.f);
                bijs[t] = bij;
                float mx = bij;
                mx = fmaxf(mx, __shfl_xor(mx, 1));
                mx = fmaxf(mx, __shfl_xor(mx, 2));
                mx = fmaxf(mx, __shfl_xor(mx, 4));
                float e = __expf(bij - mx);
                float se = e;
                se += __shfl_xor(se, 1);
                se += __shfl_xor(se, 2);
                se += __shfl_xor(se, 4);
                cijs[t] = e * __builtin_amdgcn_rcpf(se);
            }
            __syncthreads();
        }
    }
}

// ---------------------------------------------------------------------------
// [pixel][boc] -> [boc][pixel] tiled transpose (fallback path only)
// ---------------------------------------------------------------------------
__global__ void transpose_kernel(const float* __restrict__ vtmp,
                                 float* __restrict__ out)
{
    __shared__ float tile[32][33];
    const int bp = blockIdx.x;
    const int bc = blockIdx.y;
    const int p0 = bp * 32, c0 = bc * 32;
    const int tx = threadIdx.x & 31, ty = threadIdx.x >> 5;

    for (int r = ty; r < 32; r += 8) {
        const int p = p0 + r;
        tile[r][tx] = (p < NPIX) ? vtmp[(size_t)p * 2048 + c0 + tx] : 0.f;
    }
    __syncthreads();
    for (int r = ty; r < 32; r += 8) {
        const int c = c0 + r;
        const int p = p0 + tx;
        if (p < NPIX) out[(size_t)c * NPIX + p] = tile[tx][r];
    }
}

// ---------------------------------------------------------------------------
// Round-1 fp32 fallback (proven correct) — used only if ws too small
// ---------------------------------------------------------------------------
__launch_bounds__(256, 2)
__global__ void capsconv_fp32(const float* __restrict__ x,
                              const float* __restrict__ Wc,
                              const float* __restrict__ bias,
                              float* __restrict__ outbuf,
                              const int direct_out)
{
    __shared__ float As[KC][BI];
    __shared__ float Bsh[KC][NOC];
    __shared__ float cij[64];
    __shared__ float bijs2[64];
    __shared__ float aTmp2[BB * 64];

    const int t  = threadIdx.x;
    const int tn = t & 15;
    const int tm = t >> 4;
    const int p  = blockIdx.x;
    const int px = p / OWH;
    const int py = p % OWH;
    const int row0 = 2 * px - 2;
    const int col0 = 2 * py - 2;
    const bool interior = (px >= 1 && px <= 63 && py >= 1 && py <= 63);

    float C[8][8];
#pragma unroll
    for (int r = 0; r < 8; ++r)
#pragma unroll
        for (int j = 0; j < 8; ++j) C[r][j] = 0.f;

    float areg[8][4];
    float breg[32];

    auto load_chunk = [&](int kc) {
#pragma unroll
        for (int g = 0; g < 8; ++g) {
            const int L    = g * 256 + t;
            const int bi   = L & 127;
            const int cikw = L >> 7;
            const int ci   = kc * 4 + (cikw >> 2);
            const int kw   = cikw & 3;
            const int row  = row0 + kw;
            const float* src = x + (((size_t)(bi * CIN + ci) * WH + row) * WH + col0);
            if (interior) {
                const float2 v01 = *(const float2*)(src);
                const float2 v23 = *(const float2*)(src + 2);
                areg[g][0] = v01.x; areg[g][1] = v01.y;
                areg[g][2] = v23.x; areg[g][3] = v23.y;
            } else {
#pragma unroll
                for (int kh = 0; kh < 4; ++kh) {
                    const int col = col0 + kh;
                    areg[g][kh] = (row >= 0 && row < WH && col >= 0 && col < WH)
                                      ? src[kh] : 0.f;
                }
            }
        }
        {
            const int oc  = t >> 1;
            const int kk0 = (t & 1) * 32;
            const float* wsrc = Wc + (size_t)oc * KTOT + kc * KC + kk0;
#pragma unroll
            for (int m = 0; m < 32; m += 4) {
                const float4 v = *(const float4*)(wsrc + m);
                breg[m] = v.x; breg[m+1] = v.y; breg[m+2] = v.z; breg[m+3] = v.w;
            }
        }
    };

    load_chunk(0);
    for (int kc = 0; kc < NCHUNK; ++kc) {
        __syncthreads();
#pragma unroll
        for (int g = 0; g < 8; ++g) {
            const int L    = g * 256 + t;
            const int bi   = L & 127;
            const int cikw = L >> 7;
            const int kkb  = cikw * 4;
#pragma unroll
            for (int kh = 0; kh < 4; ++kh) As[kkb + kh][bi] = areg[g][kh];
        }
        {
            const int oc  = t >> 1;
            const int kk0 = (t & 1) * 32;
#pragma unroll
            for (int m = 0; m < 32; ++m) Bsh[kk0 + m][oc] = breg[m];
        }
        __syncthreads();
        if (kc < NCHUNK - 1) load_chunk(kc + 1);
#pragma unroll 4
        for (int k = 0; k < KC; ++k) {
            float af[8], bf[8];
            *(float4*)(af)     = *(const float4*)&As[k][tm * 8];
            *(float4*)(af + 4) = *(const float4*)&As[k][tm * 8 + 4];
            *(float4*)(bf)     = *(const float4*)&Bsh[k][tn * 8];
            *(float4*)(bf + 4) = *(const float4*)&Bsh[k][tn * 8 + 4];
#pragma unroll
            for (int r = 0; r < 8; ++r)
#pragma unroll
                for (int j = 0; j < 8; ++j)
                    C[r][j] = fmaf(af[r], bf[j], C[r][j]);
        }
    }
#pragma unroll
    for (int j = 0; j < 8; ++j) {
        const float bj = bias[tn * 8 + j];
#pragma unroll
        for (int r = 0; r < 8; ++r) C[r][j] += bj;
    }

    const int o = tn >> 1;
    __syncthreads();
    if (t < 64) bijs2[t] = 0.f;

    float vout[8];
    for (int it = 0; it < 3; ++it) {
        __syncthreads();
        if (t < 8) {
            const int oo = t;
            float mx = -1e30f;
#pragma unroll
            for (int i = 0; i < 8; ++i) mx = fmaxf(mx, bijs2[i * 8 + oo]);
            float e[8]; float ssum = 0.f;
#pragma unroll
            for (int i = 0; i < 8; ++i) { e[i] = expf(bijs2[i * 8 + oo] - mx); ssum += e[i]; }
            const float inv = 1.f / ssum;
#pragma unroll
            for (int i = 0; i < 8; ++i) cij[i * 8 + oo] = e[i] * inv;
        }
        __syncthreads();
        float cf[8];
#pragma unroll
        for (int i = 0; i < 8; ++i) cf[i] = cij[i * 8 + o];
        float s[8];
#pragma unroll
        for (int j = 0; j < 8; ++j) {
            float acc = 0.f;
#pragma unroll
            for (int r = 0; r < 8; ++r) acc = fmaf(cf[r], C[r][j], acc);
            s[j] = acc;
        }
        float ssq = 0.f;
#pragma unroll
        for (int j = 0; j < 8; ++j) ssq = fmaf(s[j], s[j], ssq);
        ssq += __shfl_xor(ssq, 1);
        const float scale = ssq / ((1.f + ssq) * sqrtf(ssq));
        if (it == 2) {
#pragma unroll
            for (int j = 0; j < 8; ++j) vout[j] = s[j] * scale;
        } else {
            float ap[8];
#pragma unroll
            for (int r = 0; r < 8; ++r) {
                float acc = 0.f;
#pragma unroll
                for (int j = 0; j < 8; ++j) acc = fmaf(C[r][j], s[j] * scale, acc);
                ap[r] = acc;
            }
#pragma unroll
            for (int r = 0; r < 8; ++r) ap[r] += __shfl_xor(ap[r], 1);
            if ((tn & 1) == 0) {
#pragma unroll
                for (int r = 0; r < 8; ++r) aTmp2[tm * 64 + r * 8 + o] = ap[r];
            }
            __syncthreads();
            if (t < 64) {
                float acc = 0.f;
#pragma unroll
                for (int b = 0; b < BB; ++b) acc += aTmp2[b * 64 + t];
                bijs2[t] += acc * (1.f / 16.f);
            }
        }
    }
    if (direct_out) {
#pragma unroll
        for (int j = 0; j < 8; ++j)
            outbuf[(size_t)(tm * NOC + tn * 8 + j) * NPIX + p] = vout[j];
    } else {
        float4* dst = (float4*)(outbuf + (size_t)p * 2048 + tm * NOC + tn * 8);
        dst[0] = make_float4(vout[0], vout[1], vout[2], vout[3]);
        dst[1] = make_float4(vout[4], vout[5], vout[6], vout[7]);
    }
}

extern "C" void kernel_launch(void* const* d_in, const int* in_sizes, int n_in,
                              void* d_out, int out_size, void* d_ws, size_t ws_size,
                              hipStream_t stream)
{
    const float* x    = (const float*)d_in[0];
    const float* Wc   = (const float*)d_in[1];
    const float* bias = (const float*)d_in[2];
    float* out        = (float*)d_out;

    const size_t VT_BYTES = (size_t)NPIX * 2048 * sizeof(float);   // 34,611,200
    const size_t WB_OFF   = VT_BYTES;
    const size_t XB_OFF   = WB_OFF + 65536;
    const size_t TOTAL    = XB_OFF + (size_t)BI * CIN * WH * WH * 2;  // 101,785,600

    if (ws_size >= TOTAL) {
        ushortT* Wbf  = (ushortT*)((char*)d_ws + WB_OFF);
        ushortT* xbfT = (ushortT*)((char*)d_ws + XB_OFF);

        cvtT_kernel<<<S_TOTAL / 64, 256, 0, stream>>>(x, xbfT);
        prep_w_kernel<<<128, 256, 0, stream>>>(Wc, Wbf);
        capsconv_mfma<<<529 * 8, 512, 0, stream>>>(xbfT, Wbf, bias, out, 1);
    } else if (ws_size >= VT_BYTES) {
        float* vtmp = (float*)d_ws;
        capsconv_fp32<<<NPIX, 256, 0, stream>>>(x, Wc, bias, vtmp, 0);
        dim3 g((NPIX + 31) / 32, 2048 / 32);
        transpose_kernel<<<g, 256, 0, stream>>>(vtmp, out);
    } else {
        capsconv_fp32<<<NPIX, 256, 0, stream>>>(x, Wc, bias, out, 1);
    }
}